// Round 11
// baseline (192.186 us; speedup 1.0000x reference)
//
#include <hip/hip_runtime.h>
#include <hip/hip_bf16.h>
#include <string.h>

#define NN 100000
#define NE 1600000
#define INF_ 128
#define OC 128   // NHEAD*OUT_F
#define NH 4
#define ALPHA 0.2f
#define LDA 272                      // GEMM LDS row stride in bytes

#define BSH 9
#define BINW 512                     // nodes per bin
#define NBIN ((NN + BINW - 1) / BINW)   // 196
#define EPT 16                       // edges per thread, partition kernels
#define EPB (256 * EPT)              // 4096 edges per block
#define NPB1 ((NE + EPB - 1) / EPB)  // 391 blocks
#define CAP2 12288                   // LDS staging capacity in k_part2

typedef __bf16 bf16x8 __attribute__((ext_vector_type(8)));
typedef float f32x4 __attribute__((ext_vector_type(4)));
typedef float f32x2 __attribute__((ext_vector_type(2)));

__device__ __forceinline__ float lrelu(float x) {
    return x > 0.0f ? x : ALPHA * x;
}
__device__ __forceinline__ unsigned short f2bf(float f) {
    __hip_bfloat16 b = __float2bfloat16(f);
    unsigned short u; memcpy(&u, &b, 2); return u;
}

// One-time: W [k][c] fp32 -> Wt [c][k] bf16 (32 KB).
__global__ __launch_bounds__(256) void k_wconv(
    const float* __restrict__ W, __hip_bfloat16* __restrict__ Wt) {
    const int i = blockIdx.x * 256 + threadIdx.x;   // < 16384
    const int co = i >> 7, ko = i & 127;
    Wt[i] = __float2bfloat16(W[ko * OC + co]);
}

// MFMA GEMM: h = x @ W (bf16 out) + fused al/ar epilogue.
// A fragments loaded directly from global x (rows are wave-private); only
// Wt staged in LDS (35 KB -> 4 blocks/CU).
__global__ __launch_bounds__(256) void k_gemm(
    const float* __restrict__ x, const __hip_bfloat16* __restrict__ Wt,
    const float* __restrict__ a_l, const float* __restrict__ a_r,
    __hip_bfloat16* __restrict__ hb, float* __restrict__ al, float* __restrict__ ar) {
    __shared__ __align__(16) char sB[128 * LDA];   // Wt, bf16 [col][k]
    const int tid = threadIdx.x;
    const int rowBase = blockIdx.x * 64;

    // Stage Wt (pure copy, coalesced).
    for (int i4 = tid; i4 < 2048; i4 += 256) {
        const int c = i4 >> 4, k4 = i4 & 15;
        *(uint4*)(sB + c * LDA + k4 * 16) =
            *(const uint4*)((const char*)Wt + (size_t)c * 256 + k4 * 16);
    }
    __syncthreads();

    const int lane = tid & 63;
    const int w = tid >> 6;
    const int arow = w * 16 + (lane & 15);
    const int grow = rowBase + arow;
    const int growc = (grow < NN) ? grow : (NN - 1);
    const int koff8 = (lane >> 4) * 8;       // float offset of lane's k-group
    const int koff = (lane >> 4) * 16;       // byte offset in sB rows

    f32x4 acc[8];
#pragma unroll
    for (int n = 0; n < 8; ++n) acc[n] = (f32x4){0.f, 0.f, 0.f, 0.f};

#pragma unroll
    for (int kk = 0; kk < 4; ++kk) {
        const float* xp = x + (size_t)growc * INF_ + kk * 32 + koff8;
        const float4 f0 = *(const float4*)xp;
        const float4 f1 = *(const float4*)(xp + 4);
        union { bf16x8 v; unsigned short u[8]; } au;
        au.u[0] = f2bf(f0.x); au.u[1] = f2bf(f0.y);
        au.u[2] = f2bf(f0.z); au.u[3] = f2bf(f0.w);
        au.u[4] = f2bf(f1.x); au.u[5] = f2bf(f1.y);
        au.u[6] = f2bf(f1.z); au.u[7] = f2bf(f1.w);
#pragma unroll
        for (int n = 0; n < 8; ++n) {
            const int brow = n * 16 + (lane & 15);
            const bf16x8 b = *(const bf16x8*)(sB + brow * LDA + kk * 64 + koff);
            acc[n] = __builtin_amdgcn_mfma_f32_16x16x32_bf16(au.v, b, acc[n], 0, 0, 0);
        }
    }

    // C store: col = n*16 + (lane&15), row = rbase + r.
    const int rbase = rowBase + w * 16 + (lane >> 4) * 4;
#pragma unroll
    for (int n = 0; n < 8; ++n) {
        const int col = n * 16 + (lane & 15);
#pragma unroll
        for (int r = 0; r < 4; ++r) {
            const int row = rbase + r;
            if (row < NN) hb[(size_t)row * OC + col] = __float2bfloat16(acc[n][r]);
        }
    }

    // Fused al/ar: head hd covers cols hd*32..hd*32+31 = fragments n=2hd,2hd+1.
    float alw[8], arw[8];
#pragma unroll
    for (int n = 0; n < 8; ++n) {
        alw[n] = a_l[n * 16 + (lane & 15)];
        arw[n] = a_r[n * 16 + (lane & 15)];
    }
#pragma unroll
    for (int r = 0; r < 4; ++r) {
        const int row = rbase + r;
#pragma unroll
        for (int hd = 0; hd < 4; ++hd) {
            float pl = acc[2 * hd][r] * alw[2 * hd] + acc[2 * hd + 1][r] * alw[2 * hd + 1];
            float pr = acc[2 * hd][r] * arw[2 * hd] + acc[2 * hd + 1][r] * arw[2 * hd + 1];
#pragma unroll
            for (int m = 1; m <= 8; m <<= 1) {
                pl += __shfl_xor(pl, m);
                pr += __shfl_xor(pr, m);
            }
            if ((lane & 15) == hd && row < NN) {
                al[row * NH + hd] = pl;
                ar[row * NH + hd] = pr;
            }
        }
    }
}

// Per-bin edge counts (LDS pre-aggregated).
__global__ __launch_bounds__(256) void k_binhist(
    const int* __restrict__ row, int* __restrict__ bincnt) {
    __shared__ int h[NBIN];
    const int t = threadIdx.x;
    for (int i = t; i < NBIN; i += 256) h[i] = 0;
    __syncthreads();
    const int base = blockIdx.x * EPB;
    for (int i = 0; i < EPT; ++i) {
        const int e = base + t + i * 256;
        if (e < NE) atomicAdd(&h[row[e] >> BSH], 1);
    }
    __syncthreads();
    for (int i = t; i < NBIN; i += 256)
        if (h[i]) atomicAdd(&bincnt[i], h[i]);
}

// Parallel scan of bin counts -> binoffs, bincur; also offs[NN].
__global__ __launch_bounds__(256) void k_binscan(
    const int* __restrict__ bincnt, int* __restrict__ binoffs,
    int* __restrict__ bincur, int* __restrict__ offs) {
    __shared__ int ts[256];
    const int t = threadIdx.x;
    const int v = (t < NBIN) ? bincnt[t] : 0;
    ts[t] = v;
    __syncthreads();
    for (int o = 1; o < 256; o <<= 1) {
        const int add = (t >= o) ? ts[t - o] : 0;
        __syncthreads();
        ts[t] += add;
        __syncthreads();
    }
    const int ex = ts[t] - v;
    if (t < NBIN) { binoffs[t] = ex; bincur[t] = ex; }
    if (t == 255) {
        binoffs[NBIN] = ts[255];   // == NE
        offs[NN] = NE;
    }
}

// Coarse partition: edges -> bin-grouped packed words ((r&511)<<17 | c).
__global__ __launch_bounds__(256) void k_part1(
    const int* __restrict__ row, const int* __restrict__ col,
    int* __restrict__ bincur, unsigned* __restrict__ tmp) {
    __shared__ int h[NBIN], gbase[NBIN], lcur[NBIN];
    const int t = threadIdx.x;
    for (int i = t; i < NBIN; i += 256) { h[i] = 0; lcur[i] = 0; }
    __syncthreads();

    const int e0 = blockIdx.x * EPB + t * EPT;
    int r[EPT], c[EPT];
    if (e0 + EPT <= NE) {
#pragma unroll
        for (int q = 0; q < EPT / 4; ++q) {
            const int4 rv = *(const int4*)&row[e0 + q * 4];
            const int4 cv = *(const int4*)&col[e0 + q * 4];
            r[q*4+0] = rv.x; r[q*4+1] = rv.y; r[q*4+2] = rv.z; r[q*4+3] = rv.w;
            c[q*4+0] = cv.x; c[q*4+1] = cv.y; c[q*4+2] = cv.z; c[q*4+3] = cv.w;
        }
    } else {
#pragma unroll
        for (int i = 0; i < EPT; ++i) {
            const int e = e0 + i;
            r[i] = (e < NE) ? row[e] : -1;
            c[i] = (e < NE) ? col[e] : 0;
        }
    }
#pragma unroll
    for (int i = 0; i < EPT; ++i)
        if (r[i] >= 0) atomicAdd(&h[r[i] >> BSH], 1);
    __syncthreads();
    for (int i = t; i < NBIN; i += 256)
        if (h[i]) gbase[i] = atomicAdd(&bincur[i], h[i]);
    __syncthreads();
#pragma unroll
    for (int i = 0; i < EPT; ++i) {
        if (r[i] < 0) continue;
        const int b = r[i] >> BSH;
        const int pos = atomicAdd(&lcur[b], 1);
        tmp[gbase[b] + pos] =
            ((unsigned)(r[i] & (BINW - 1)) << 17) | (unsigned)c[i];
    }
}

// Fine partition: one block per bin; emits node-sorted cols_s + per-node offs.
__global__ __launch_bounds__(256) void k_part2(
    const unsigned* __restrict__ tmp, const int* __restrict__ binoffs,
    int* __restrict__ offs, int* __restrict__ cols_s) {
    __shared__ unsigned stage[CAP2];          // 48 KB
    __shared__ int h[BINW], ps[256], cur[BINW];
    const int b = blockIdx.x, t = threadIdx.x;
    const int node0 = b * BINW;
    const int gs = binoffs[b], ge = binoffs[b + 1];
    const int cnt = ge - gs;
    for (int i = t; i < BINW; i += 256) h[i] = 0;
    __syncthreads();
    for (int j = t; j < cnt; j += 256) {
        const unsigned p = tmp[gs + j];
        if (j < CAP2) stage[j] = p;
        atomicAdd(&h[p >> 17], 1);
    }
    __syncthreads();
    const int a0 = h[2 * t], a1 = h[2 * t + 1];
    ps[t] = a0 + a1;
    __syncthreads();
    for (int o = 1; o < 256; o <<= 1) {
        const int add = (t >= o) ? ps[t - o] : 0;
        __syncthreads();
        ps[t] += add;
        __syncthreads();
    }
    const int ex = ps[t] - a0 - a1 + gs;
    cur[2 * t] = ex;
    cur[2 * t + 1] = ex + a0;
    if (node0 + 2 * t < NN)     offs[node0 + 2 * t]     = ex;
    if (node0 + 2 * t + 1 < NN) offs[node0 + 2 * t + 1] = ex + a0;
    __syncthreads();
    for (int j = t; j < cnt; j += 256) {
        const unsigned p = (j < CAP2) ? stage[j] : tmp[gs + j];
        const int pos = atomicAdd(&cur[p >> 17], 1);
        cols_s[pos] = (int)(p & 0x1FFFFu);
    }
}

// Fused score + softmax + aggregation: 16-lane group per node, no cross-lane
// exchange. Every lane of a group broadcasts the same cols/ar loads and
// computes its head's weights redundantly; 8 independent h-row loads per
// chunk give deep MLP.
__global__ __launch_bounds__(256) void k_agg(
    const int* __restrict__ offs, const int* __restrict__ cols_s,
    const float* __restrict__ al, const float* __restrict__ ar,
    const __hip_bfloat16* __restrict__ hb, float* __restrict__ out) {
    const int w = threadIdx.x >> 6;
    const int lane = threadIdx.x & 63;
    const int g = lane >> 4;            // node slot within wave
    const int sl = lane & 15;           // sublane within group
    const int node = blockIdx.x * 16 + w * 4 + g;
    if (node >= NN) return;

    const int start = offs[node];
    const int deg = offs[node + 1] - start;
    const int hsel = sl >> 2;           // head owning this lane's 8 dims
    const float al_h = al[node * NH + hsel];
    const char* hrow = (const char*)hb + sl * 16;   // lane's 16B slice

    f32x2 a0 = {0.f, 0.f}, a1 = {0.f, 0.f}, a2 = {0.f, 0.f}, a3 = {0.f, 0.f};
    float ssum = 0.f;

    for (int kk = 0; kk < deg; kk += 8) {
        const int rem = deg - kk;
        // over-read of <=28B is safe: tmp[] follows cols_s in the workspace
        const int4 cA = *(const int4*)(cols_s + start + kk);
        const int4 cB = *(const int4*)(cols_s + start + kk + 4);
        int c_[8] = {cA.x, cA.y, cA.z, cA.w, cB.x, cB.y, cB.z, cB.w};
        float w_[8];
#pragma unroll
        for (int j = 0; j < 8; ++j) {
            if (j < rem) {
                w_[j] = __expf(lrelu(al_h + ar[c_[j] * NH + hsel]));
            } else { w_[j] = 0.f; c_[j] = 0; }
        }
#pragma unroll
        for (int j = 0; j < 8; ++j) {
            const uint4 v = *(const uint4*)(hrow + (size_t)c_[j] * 256);
            const float wj = w_[j];
            a0 += wj * (f32x2){__uint_as_float(v.x << 16), __uint_as_float(v.x & 0xffff0000u)};
            a1 += wj * (f32x2){__uint_as_float(v.y << 16), __uint_as_float(v.y & 0xffff0000u)};
            a2 += wj * (f32x2){__uint_as_float(v.z << 16), __uint_as_float(v.z & 0xffff0000u)};
            a3 += wj * (f32x2){__uint_as_float(v.w << 16), __uint_as_float(v.w & 0xffff0000u)};
            ssum += wj;
        }
    }

    const float inv = (ssum > 0.f) ? 1.0f / ssum : 0.f;
    float4 o0, o1;
    o0.x = a0.x * inv; o0.y = a0.y * inv; o0.z = a1.x * inv; o0.w = a1.y * inv;
    o1.x = a2.x * inv; o1.y = a2.y * inv; o1.z = a3.x * inv; o1.w = a3.y * inv;
    float* dst = out + (size_t)node * OC + sl * 8;
    *(float4*)dst = o0;
    *(float4*)(dst + 4) = o1;
}

extern "C" void kernel_launch(void* const* d_in, const int* in_sizes, int n_in,
                              void* d_out, int out_size, void* d_ws, size_t ws_size,
                              hipStream_t stream) {
    const float* x    = (const float*)d_in[0];
    const int*   ei   = (const int*)d_in[1];    // [2, NE]
    const float* W    = (const float*)d_in[2];
    const float* a_l  = (const float*)d_in[3];
    const float* a_r  = (const float*)d_in[4];
    float* out = (float*)d_out;

    const int* row = ei;         // destination
    const int* col = ei + NE;    // source

    char* ws = (char*)d_ws;
    __hip_bfloat16* hb = (__hip_bfloat16*)ws;   ws += (size_t)NN * OC * 2;   // 25.6 MB
    __hip_bfloat16* Wt = (__hip_bfloat16*)ws;   ws += (size_t)INF_ * OC * 2; // 32 KB
    float*    al      = (float*)ws;             ws += (size_t)NN * NH * 4;
    float*    ar      = (float*)ws;             ws += (size_t)NN * NH * 4;
    int*      cols_s  = (int*)ws;               ws += (size_t)NE * 4;        // 6.4 MB
    unsigned* tmp     = (unsigned*)ws;          ws += (size_t)NE * 4;        // 6.4 MB
    int*      offs    = (int*)ws;               ws += (size_t)(NN + 1) * 4;
    int*      bincnt  = (int*)ws;               ws += (size_t)(NBIN + 1) * 4;
    int*      binoffs = (int*)ws;               ws += (size_t)(NBIN + 1) * 4;
    int*      bincur  = (int*)ws;               ws += (size_t)NBIN * 4;

    hipMemsetAsync(bincnt, 0, (size_t)NBIN * 4, stream);

    k_wconv<<<64, 256, 0, stream>>>(W, Wt);
    k_gemm<<<(NN + 63) / 64, 256, 0, stream>>>(x, Wt, a_l, a_r, hb, al, ar);
    k_binhist<<<NPB1, 256, 0, stream>>>(row, bincnt);
    k_binscan<<<1, 256, 0, stream>>>(bincnt, binoffs, bincur, offs);
    k_part1<<<NPB1, 256, 0, stream>>>(row, col, bincur, tmp);
    k_part2<<<NBIN, 256, 0, stream>>>(tmp, binoffs, offs, cols_s);
    k_agg<<<(NN + 15) / 16, 256, 0, stream>>>(offs, cols_s, al, ar, hb, out);
}

// Round 12
// 172.094 us; speedup vs baseline: 1.1167x; 1.1167x over previous
//
#include <hip/hip_runtime.h>
#include <hip/hip_bf16.h>
#include <string.h>

#define NN 100000
#define NE 1600000
#define INF_ 128
#define OC 128   // NHEAD*OUT_F
#define NH 4
#define ALPHA 0.2f
#define LDA 272                      // GEMM LDS row stride in bytes

#define BSH 9
#define BINW 512                     // nodes per bin
#define NBIN ((NN + BINW - 1) / BINW)   // 196
#define EPT 16                       // edges per thread, partition kernels
#define EPB (256 * EPT)              // 4096 edges per block
#define NPB1 ((NE + EPB - 1) / EPB)  // 391 blocks
#define CAP2 12288                   // LDS staging capacity in k_part2

typedef __bf16 bf16x8 __attribute__((ext_vector_type(8)));
typedef float f32x4 __attribute__((ext_vector_type(4)));
typedef float f32x2 __attribute__((ext_vector_type(2)));

__device__ __forceinline__ float lrelu(float x) {
    return x > 0.0f ? x : ALPHA * x;
}
__device__ __forceinline__ unsigned short f2bf(float f) {
    __hip_bfloat16 b = __float2bfloat16(f);
    unsigned short u; memcpy(&u, &b, 2); return u;
}
__device__ __forceinline__ int sel4(const int4 v, int j) {
    // j in 0..3, runtime: 2-level cndmask select (avoids scratch array)
    const int lo = (j & 1) ? v.y : v.x;
    const int hi = (j & 1) ? v.w : v.z;
    return (j & 2) ? hi : lo;
}

// One-time: W [k][c] fp32 -> Wt [c][k] bf16 (32 KB).
__global__ __launch_bounds__(256) void k_wconv(
    const float* __restrict__ W, __hip_bfloat16* __restrict__ Wt) {
    const int i = blockIdx.x * 256 + threadIdx.x;   // < 16384
    const int co = i >> 7, ko = i & 127;
    Wt[i] = __float2bfloat16(W[ko * OC + co]);
}

// MFMA GEMM: h = x @ W (bf16 out) + fused al/ar epilogue.
// A fragments loaded directly from global x; only Wt staged in LDS.
__global__ __launch_bounds__(256) void k_gemm(
    const float* __restrict__ x, const __hip_bfloat16* __restrict__ Wt,
    const float* __restrict__ a_l, const float* __restrict__ a_r,
    __hip_bfloat16* __restrict__ hb, float* __restrict__ al, float* __restrict__ ar) {
    __shared__ __align__(16) char sB[128 * LDA];   // Wt, bf16 [col][k]
    const int tid = threadIdx.x;
    const int rowBase = blockIdx.x * 64;

    for (int i4 = tid; i4 < 2048; i4 += 256) {
        const int c = i4 >> 4, k4 = i4 & 15;
        *(uint4*)(sB + c * LDA + k4 * 16) =
            *(const uint4*)((const char*)Wt + (size_t)c * 256 + k4 * 16);
    }
    __syncthreads();

    const int lane = tid & 63;
    const int w = tid >> 6;
    const int arow = w * 16 + (lane & 15);
    const int grow = rowBase + arow;
    const int growc = (grow < NN) ? grow : (NN - 1);
    const int koff8 = (lane >> 4) * 8;
    const int koff = (lane >> 4) * 16;

    f32x4 acc[8];
#pragma unroll
    for (int n = 0; n < 8; ++n) acc[n] = (f32x4){0.f, 0.f, 0.f, 0.f};

#pragma unroll
    for (int kk = 0; kk < 4; ++kk) {
        const float* xp = x + (size_t)growc * INF_ + kk * 32 + koff8;
        const float4 f0 = *(const float4*)xp;
        const float4 f1 = *(const float4*)(xp + 4);
        union { bf16x8 v; unsigned short u[8]; } au;
        au.u[0] = f2bf(f0.x); au.u[1] = f2bf(f0.y);
        au.u[2] = f2bf(f0.z); au.u[3] = f2bf(f0.w);
        au.u[4] = f2bf(f1.x); au.u[5] = f2bf(f1.y);
        au.u[6] = f2bf(f1.z); au.u[7] = f2bf(f1.w);
#pragma unroll
        for (int n = 0; n < 8; ++n) {
            const int brow = n * 16 + (lane & 15);
            const bf16x8 b = *(const bf16x8*)(sB + brow * LDA + kk * 64 + koff);
            acc[n] = __builtin_amdgcn_mfma_f32_16x16x32_bf16(au.v, b, acc[n], 0, 0, 0);
        }
    }

    const int rbase = rowBase + w * 16 + (lane >> 4) * 4;
#pragma unroll
    for (int n = 0; n < 8; ++n) {
        const int col = n * 16 + (lane & 15);
#pragma unroll
        for (int r = 0; r < 4; ++r) {
            const int row = rbase + r;
            if (row < NN) hb[(size_t)row * OC + col] = __float2bfloat16(acc[n][r]);
        }
    }

    float alw[8], arw[8];
#pragma unroll
    for (int n = 0; n < 8; ++n) {
        alw[n] = a_l[n * 16 + (lane & 15)];
        arw[n] = a_r[n * 16 + (lane & 15)];
    }
#pragma unroll
    for (int r = 0; r < 4; ++r) {
        const int row = rbase + r;
#pragma unroll
        for (int hd = 0; hd < 4; ++hd) {
            float pl = acc[2 * hd][r] * alw[2 * hd] + acc[2 * hd + 1][r] * alw[2 * hd + 1];
            float pr = acc[2 * hd][r] * arw[2 * hd] + acc[2 * hd + 1][r] * arw[2 * hd + 1];
#pragma unroll
            for (int m = 1; m <= 8; m <<= 1) {
                pl += __shfl_xor(pl, m);
                pr += __shfl_xor(pr, m);
            }
            if ((lane & 15) == hd && row < NN) {
                al[row * NH + hd] = pl;
                ar[row * NH + hd] = pr;
            }
        }
    }
}

// Per-bin edge counts (LDS pre-aggregated).
__global__ __launch_bounds__(256) void k_binhist(
    const int* __restrict__ row, int* __restrict__ bincnt) {
    __shared__ int h[NBIN];
    const int t = threadIdx.x;
    for (int i = t; i < NBIN; i += 256) h[i] = 0;
    __syncthreads();
    const int base = blockIdx.x * EPB;
    for (int i = 0; i < EPT; ++i) {
        const int e = base + t + i * 256;
        if (e < NE) atomicAdd(&h[row[e] >> BSH], 1);
    }
    __syncthreads();
    for (int i = t; i < NBIN; i += 256)
        if (h[i]) atomicAdd(&bincnt[i], h[i]);
}

// Parallel scan of bin counts -> binoffs, bincur; also offs[NN].
__global__ __launch_bounds__(256) void k_binscan(
    const int* __restrict__ bincnt, int* __restrict__ binoffs,
    int* __restrict__ bincur, int* __restrict__ offs) {
    __shared__ int ts[256];
    const int t = threadIdx.x;
    const int v = (t < NBIN) ? bincnt[t] : 0;
    ts[t] = v;
    __syncthreads();
    for (int o = 1; o < 256; o <<= 1) {
        const int add = (t >= o) ? ts[t - o] : 0;
        __syncthreads();
        ts[t] += add;
        __syncthreads();
    }
    const int ex = ts[t] - v;
    if (t < NBIN) { binoffs[t] = ex; bincur[t] = ex; }
    if (t == 255) {
        binoffs[NBIN] = ts[255];   // == NE
        offs[NN] = NE;
    }
}

// Coarse partition: edges -> bin-grouped packed words ((r&511)<<17 | c).
__global__ __launch_bounds__(256) void k_part1(
    const int* __restrict__ row, const int* __restrict__ col,
    int* __restrict__ bincur, unsigned* __restrict__ tmp) {
    __shared__ int h[NBIN], gbase[NBIN], lcur[NBIN];
    const int t = threadIdx.x;
    for (int i = t; i < NBIN; i += 256) { h[i] = 0; lcur[i] = 0; }
    __syncthreads();

    const int e0 = blockIdx.x * EPB + t * EPT;
    int r[EPT], c[EPT];
    if (e0 + EPT <= NE) {
#pragma unroll
        for (int q = 0; q < EPT / 4; ++q) {
            const int4 rv = *(const int4*)&row[e0 + q * 4];
            const int4 cv = *(const int4*)&col[e0 + q * 4];
            r[q*4+0] = rv.x; r[q*4+1] = rv.y; r[q*4+2] = rv.z; r[q*4+3] = rv.w;
            c[q*4+0] = cv.x; c[q*4+1] = cv.y; c[q*4+2] = cv.z; c[q*4+3] = cv.w;
        }
    } else {
#pragma unroll
        for (int i = 0; i < EPT; ++i) {
            const int e = e0 + i;
            r[i] = (e < NE) ? row[e] : -1;
            c[i] = (e < NE) ? col[e] : 0;
        }
    }
#pragma unroll
    for (int i = 0; i < EPT; ++i)
        if (r[i] >= 0) atomicAdd(&h[r[i] >> BSH], 1);
    __syncthreads();
    for (int i = t; i < NBIN; i += 256)
        if (h[i]) gbase[i] = atomicAdd(&bincur[i], h[i]);
    __syncthreads();
#pragma unroll
    for (int i = 0; i < EPT; ++i) {
        if (r[i] < 0) continue;
        const int b = r[i] >> BSH;
        const int pos = atomicAdd(&lcur[b], 1);
        tmp[gbase[b] + pos] =
            ((unsigned)(r[i] & (BINW - 1)) << 17) | (unsigned)c[i];
    }
}

// Fine partition: one block per bin; emits node-sorted cols_s + per-node offs.
__global__ __launch_bounds__(256) void k_part2(
    const unsigned* __restrict__ tmp, const int* __restrict__ binoffs,
    int* __restrict__ offs, int* __restrict__ cols_s) {
    __shared__ unsigned stage[CAP2];          // 48 KB
    __shared__ int h[BINW], ps[256], cur[BINW];
    const int b = blockIdx.x, t = threadIdx.x;
    const int node0 = b * BINW;
    const int gs = binoffs[b], ge = binoffs[b + 1];
    const int cnt = ge - gs;
    for (int i = t; i < BINW; i += 256) h[i] = 0;
    __syncthreads();
    for (int j = t; j < cnt; j += 256) {
        const unsigned p = tmp[gs + j];
        if (j < CAP2) stage[j] = p;
        atomicAdd(&h[p >> 17], 1);
    }
    __syncthreads();
    const int a0 = h[2 * t], a1 = h[2 * t + 1];
    ps[t] = a0 + a1;
    __syncthreads();
    for (int o = 1; o < 256; o <<= 1) {
        const int add = (t >= o) ? ps[t - o] : 0;
        __syncthreads();
        ps[t] += add;
        __syncthreads();
    }
    const int ex = ps[t] - a0 - a1 + gs;
    cur[2 * t] = ex;
    cur[2 * t + 1] = ex + a0;
    if (node0 + 2 * t < NN)     offs[node0 + 2 * t]     = ex;
    if (node0 + 2 * t + 1 < NN) offs[node0 + 2 * t + 1] = ex + a0;
    __syncthreads();
    for (int j = t; j < cnt; j += 256) {
        const unsigned p = (j < CAP2) ? stage[j] : tmp[gs + j];
        const int pos = atomicAdd(&cur[p >> 17], 1);
        cols_s[pos] = (int)(p & 0x1FFFFu);
    }
}

// Fused score + softmax + aggregation: 16-lane group per node.
// Hybrid: cols broadcast-loaded by all lanes (lane-local h addresses, no
// shfl in the address path); scoring split across lanes (1 ar load + 1 exp
// per 4 edges); weights exchanged via shfl off the critical path.
__global__ __launch_bounds__(256) void k_agg(
    const int* __restrict__ offs, const int* __restrict__ cols_s,
    const float* __restrict__ al, const float* __restrict__ ar,
    const __hip_bfloat16* __restrict__ hb, float* __restrict__ out) {
    const int w = threadIdx.x >> 6;
    const int lane = threadIdx.x & 63;
    const int g = lane >> 4;            // node slot within wave
    const int sl = lane & 15;           // sublane within group
    const int node = blockIdx.x * 16 + w * 4 + g;
    if (node >= NN) return;

    const int start = offs[node];
    const int deg = offs[node + 1] - start;
    const int hsel = sl >> 2;           // head owning this lane's 8 dims
    const int je = sl >> 2;             // edge slot this lane scores
    const int sh = sl & 3;              // head this lane scores
    const int sbase = lane & 48;        // group base lane
    const float al_sh = al[node * NH + sh];
    const char* hrow = (const char*)hb + sl * 16;   // lane's 16B slice

    f32x2 a0 = {0.f, 0.f}, a1 = {0.f, 0.f}, a2 = {0.f, 0.f}, a3 = {0.f, 0.f};
    float ssum = 0.f;

    // over-reads (<=60B past segment end) land in cols_s/tmp buffers: safe.
    int4 cA = *(const int4*)(cols_s + start);
    int4 cB = *(const int4*)(cols_s + start + 4);

    for (int kk = 0; kk < deg; kk += 8) {
        const int rem = deg - kk;
        const int4 cA2 = *(const int4*)(cols_s + start + kk + 8);
        const int4 cB2 = *(const int4*)(cols_s + start + kk + 12);

        // scoring: lane (je, sh) handles edges kk+je and kk+4+je
        float wvA = 0.f, wvB = 0.f;
        if (je < rem) {
            const int c = sel4(cA, je);
            wvA = __expf(lrelu(al_sh + ar[c * NH + sh]));
        }
        if (je + 4 < rem) {
            const int c = sel4(cB, je);
            wvB = __expf(lrelu(al_sh + ar[c * NH + sh]));
        }

        int c_[8] = {cA.x, cA.y, cA.z, cA.w, cB.x, cB.y, cB.z, cB.w};
#pragma unroll
        for (int j = 0; j < 8; ++j)
            if (j >= rem) c_[j] = 0;

#pragma unroll
        for (int j = 0; j < 8; ++j) {
            const float wj = __shfl(j < 4 ? wvA : wvB, sbase + (j & 3) * 4 + hsel);
            const uint4 v = *(const uint4*)(hrow + (size_t)c_[j] * 256);
            a0 += wj * (f32x2){__uint_as_float(v.x << 16), __uint_as_float(v.x & 0xffff0000u)};
            a1 += wj * (f32x2){__uint_as_float(v.y << 16), __uint_as_float(v.y & 0xffff0000u)};
            a2 += wj * (f32x2){__uint_as_float(v.z << 16), __uint_as_float(v.z & 0xffff0000u)};
            a3 += wj * (f32x2){__uint_as_float(v.w << 16), __uint_as_float(v.w & 0xffff0000u)};
            ssum += wj;
        }
        cA = cA2; cB = cB2;
    }

    const float inv = (ssum > 0.f) ? 1.0f / ssum : 0.f;
    float4 o0, o1;
    o0.x = a0.x * inv; o0.y = a0.y * inv; o0.z = a1.x * inv; o0.w = a1.y * inv;
    o1.x = a2.x * inv; o1.y = a2.y * inv; o1.z = a3.x * inv; o1.w = a3.y * inv;
    float* dst = out + (size_t)node * OC + sl * 8;
    *(float4*)dst = o0;
    *(float4*)(dst + 4) = o1;
}

extern "C" void kernel_launch(void* const* d_in, const int* in_sizes, int n_in,
                              void* d_out, int out_size, void* d_ws, size_t ws_size,
                              hipStream_t stream) {
    const float* x    = (const float*)d_in[0];
    const int*   ei   = (const int*)d_in[1];    // [2, NE]
    const float* W    = (const float*)d_in[2];
    const float* a_l  = (const float*)d_in[3];
    const float* a_r  = (const float*)d_in[4];
    float* out = (float*)d_out;

    const int* row = ei;         // destination
    const int* col = ei + NE;    // source

    char* ws = (char*)d_ws;
    __hip_bfloat16* hb = (__hip_bfloat16*)ws;   ws += (size_t)NN * OC * 2;   // 25.6 MB
    __hip_bfloat16* Wt = (__hip_bfloat16*)ws;   ws += (size_t)INF_ * OC * 2; // 32 KB
    float*    al      = (float*)ws;             ws += (size_t)NN * NH * 4;
    float*    ar      = (float*)ws;             ws += (size_t)NN * NH * 4;
    int*      cols_s  = (int*)ws;               ws += (size_t)NE * 4;        // 6.4 MB
    unsigned* tmp     = (unsigned*)ws;          ws += (size_t)NE * 4;        // 6.4 MB
    int*      offs    = (int*)ws;               ws += (size_t)(NN + 1) * 4;
    int*      bincnt  = (int*)ws;               ws += (size_t)(NBIN + 1) * 4;
    int*      binoffs = (int*)ws;               ws += (size_t)(NBIN + 1) * 4;
    int*      bincur  = (int*)ws;               ws += (size_t)NBIN * 4;

    hipMemsetAsync(bincnt, 0, (size_t)NBIN * 4, stream);

    k_wconv<<<64, 256, 0, stream>>>(W, Wt);
    k_gemm<<<(NN + 63) / 64, 256, 0, stream>>>(x, Wt, a_l, a_r, hb, al, ar);
    k_binhist<<<NPB1, 256, 0, stream>>>(row, bincnt);
    k_binscan<<<1, 256, 0, stream>>>(bincnt, binoffs, bincur, offs);
    k_part1<<<NPB1, 256, 0, stream>>>(row, col, bincur, tmp);
    k_part2<<<NBIN, 256, 0, stream>>>(tmp, binoffs, offs, cols_s);
    k_agg<<<(NN + 15) / 16, 256, 0, stream>>>(offs, cols_s, al, ar, hb, out);
}

// Round 13
// 158.770 us; speedup vs baseline: 1.2105x; 1.0839x over previous
//
#include <hip/hip_runtime.h>
#include <hip/hip_bf16.h>
#include <string.h>

#define NN 100000
#define NE 1600000
#define INF_ 128
#define OC 128   // NHEAD*OUT_F
#define NH 4
#define ALPHA 0.2f
#define LDA 272                      // GEMM LDS row stride in bytes

#define BSH 9
#define BINW 512                     // nodes per bin
#define NBIN ((NN + BINW - 1) / BINW)   // 196
#define EPT 16                       // edges per thread, partition kernels
#define EPB (256 * EPT)              // 4096 edges per block
#define NPB1 ((NE + EPB - 1) / EPB)  // 391 blocks
#define CAP2 12288                   // LDS staging capacity in k_part2

typedef __bf16 bf16x8 __attribute__((ext_vector_type(8)));
typedef float f32x4 __attribute__((ext_vector_type(4)));
typedef float f32x2 __attribute__((ext_vector_type(2)));

__device__ __forceinline__ float lrelu(float x) {
    return x > 0.0f ? x : ALPHA * x;
}
__device__ __forceinline__ unsigned short f2bf(float f) {
    __hip_bfloat16 b = __float2bfloat16(f);
    unsigned short u; memcpy(&u, &b, 2); return u;
}
__device__ __forceinline__ int sel4(const int4 v, int j) {
    const int lo = (j & 1) ? v.y : v.x;
    const int hi = (j & 1) ? v.w : v.z;
    return (j & 2) ? hi : lo;
}

// One-time: W [k][c] fp32 -> Wt [c][k] bf16 (32 KB); block 0 zeroes bincnt.
__global__ __launch_bounds__(256) void k_wconv(
    const float* __restrict__ W, __hip_bfloat16* __restrict__ Wt,
    int* __restrict__ bincnt) {
    const int i = blockIdx.x * 256 + threadIdx.x;   // < 16384
    const int co = i >> 7, ko = i & 127;
    Wt[i] = __float2bfloat16(W[ko * OC + co]);
    if (blockIdx.x == 0 && threadIdx.x < NBIN) bincnt[threadIdx.x] = 0;
}

// MFMA GEMM: h = x @ W (bf16 out) + fused al/ar epilogue + fused bin histogram
// (first NPB1 blocks histogram their 4096-edge chunk of `row`).
__global__ __launch_bounds__(256) void k_gemm(
    const float* __restrict__ x, const __hip_bfloat16* __restrict__ Wt,
    const float* __restrict__ a_l, const float* __restrict__ a_r,
    __hip_bfloat16* __restrict__ hb, float* __restrict__ al, float* __restrict__ ar,
    const int* __restrict__ row, int* __restrict__ bincnt) {
    __shared__ __align__(16) char sB[128 * LDA];   // Wt, bf16 [col][k]
    __shared__ int hsh[NBIN];
    const int tid = threadIdx.x;
    const int rowBase = blockIdx.x * 64;

    for (int i4 = tid; i4 < 2048; i4 += 256) {
        const int c = i4 >> 4, k4 = i4 & 15;
        *(uint4*)(sB + c * LDA + k4 * 16) =
            *(const uint4*)((const char*)Wt + (size_t)c * 256 + k4 * 16);
    }
    __syncthreads();

    const int lane = tid & 63;
    const int w = tid >> 6;
    const int arow = w * 16 + (lane & 15);
    const int grow = rowBase + arow;
    const int growc = (grow < NN) ? grow : (NN - 1);
    const int koff8 = (lane >> 4) * 8;
    const int koff = (lane >> 4) * 16;

    f32x4 acc[8];
#pragma unroll
    for (int n = 0; n < 8; ++n) acc[n] = (f32x4){0.f, 0.f, 0.f, 0.f};

#pragma unroll
    for (int kk = 0; kk < 4; ++kk) {
        const float* xp = x + (size_t)growc * INF_ + kk * 32 + koff8;
        const float4 f0 = *(const float4*)xp;
        const float4 f1 = *(const float4*)(xp + 4);
        union { bf16x8 v; unsigned short u[8]; } au;
        au.u[0] = f2bf(f0.x); au.u[1] = f2bf(f0.y);
        au.u[2] = f2bf(f0.z); au.u[3] = f2bf(f0.w);
        au.u[4] = f2bf(f1.x); au.u[5] = f2bf(f1.y);
        au.u[6] = f2bf(f1.z); au.u[7] = f2bf(f1.w);
#pragma unroll
        for (int n = 0; n < 8; ++n) {
            const int brow = n * 16 + (lane & 15);
            const bf16x8 b = *(const bf16x8*)(sB + brow * LDA + kk * 64 + koff);
            acc[n] = __builtin_amdgcn_mfma_f32_16x16x32_bf16(au.v, b, acc[n], 0, 0, 0);
        }
    }

    const int rbase = rowBase + w * 16 + (lane >> 4) * 4;
#pragma unroll
    for (int n = 0; n < 8; ++n) {
        const int col = n * 16 + (lane & 15);
#pragma unroll
        for (int r = 0; r < 4; ++r) {
            const int rw = rbase + r;
            if (rw < NN) hb[(size_t)rw * OC + col] = __float2bfloat16(acc[n][r]);
        }
    }

    float alw[8], arw[8];
#pragma unroll
    for (int n = 0; n < 8; ++n) {
        alw[n] = a_l[n * 16 + (lane & 15)];
        arw[n] = a_r[n * 16 + (lane & 15)];
    }
#pragma unroll
    for (int r = 0; r < 4; ++r) {
        const int rw = rbase + r;
#pragma unroll
        for (int hd = 0; hd < 4; ++hd) {
            float pl = acc[2 * hd][r] * alw[2 * hd] + acc[2 * hd + 1][r] * alw[2 * hd + 1];
            float pr = acc[2 * hd][r] * arw[2 * hd] + acc[2 * hd + 1][r] * arw[2 * hd + 1];
#pragma unroll
            for (int m = 1; m <= 8; m <<= 1) {
                pl += __shfl_xor(pl, m);
                pr += __shfl_xor(pr, m);
            }
            if ((lane & 15) == hd && rw < NN) {
                al[rw * NH + hd] = pl;
                ar[rw * NH + hd] = pr;
            }
        }
    }

    // Fused bin histogram (replaces k_binhist).
    if (blockIdx.x < NPB1) {
        for (int i = tid; i < NBIN; i += 256) hsh[i] = 0;
        __syncthreads();
        const int base = blockIdx.x * EPB;
        for (int i = 0; i < EPT; ++i) {
            const int e = base + tid + i * 256;
            if (e < NE) atomicAdd(&hsh[row[e] >> BSH], 1);
        }
        __syncthreads();
        for (int i = tid; i < NBIN; i += 256)
            if (hsh[i]) atomicAdd(&bincnt[i], hsh[i]);
    }
}

// Parallel scan of bin counts -> binoffs, bincur; also offs[NN].
__global__ __launch_bounds__(256) void k_binscan(
    const int* __restrict__ bincnt, int* __restrict__ binoffs,
    int* __restrict__ bincur, int* __restrict__ offs) {
    __shared__ int ts[256];
    const int t = threadIdx.x;
    const int v = (t < NBIN) ? bincnt[t] : 0;
    ts[t] = v;
    __syncthreads();
    for (int o = 1; o < 256; o <<= 1) {
        const int add = (t >= o) ? ts[t - o] : 0;
        __syncthreads();
        ts[t] += add;
        __syncthreads();
    }
    const int ex = ts[t] - v;
    if (t < NBIN) { binoffs[t] = ex; bincur[t] = ex; }
    if (t == 255) {
        binoffs[NBIN] = ts[255];   // == NE
        offs[NN] = NE;
    }
}

// Coarse partition: edges -> bin-grouped packed words ((r&511)<<17 | c).
__global__ __launch_bounds__(256) void k_part1(
    const int* __restrict__ row, const int* __restrict__ col,
    int* __restrict__ bincur, unsigned* __restrict__ tmp) {
    __shared__ int h[NBIN], gbase[NBIN], lcur[NBIN];
    const int t = threadIdx.x;
    for (int i = t; i < NBIN; i += 256) { h[i] = 0; lcur[i] = 0; }
    __syncthreads();

    const int e0 = blockIdx.x * EPB + t * EPT;
    int r[EPT], c[EPT];
    if (e0 + EPT <= NE) {
#pragma unroll
        for (int q = 0; q < EPT / 4; ++q) {
            const int4 rv = *(const int4*)&row[e0 + q * 4];
            const int4 cv = *(const int4*)&col[e0 + q * 4];
            r[q*4+0] = rv.x; r[q*4+1] = rv.y; r[q*4+2] = rv.z; r[q*4+3] = rv.w;
            c[q*4+0] = cv.x; c[q*4+1] = cv.y; c[q*4+2] = cv.z; c[q*4+3] = cv.w;
        }
    } else {
#pragma unroll
        for (int i = 0; i < EPT; ++i) {
            const int e = e0 + i;
            r[i] = (e < NE) ? row[e] : -1;
            c[i] = (e < NE) ? col[e] : 0;
        }
    }
#pragma unroll
    for (int i = 0; i < EPT; ++i)
        if (r[i] >= 0) atomicAdd(&h[r[i] >> BSH], 1);
    __syncthreads();
    for (int i = t; i < NBIN; i += 256)
        if (h[i]) gbase[i] = atomicAdd(&bincur[i], h[i]);
    __syncthreads();
#pragma unroll
    for (int i = 0; i < EPT; ++i) {
        if (r[i] < 0) continue;
        const int b = r[i] >> BSH;
        const int pos = atomicAdd(&lcur[b], 1);
        tmp[gbase[b] + pos] =
            ((unsigned)(r[i] & (BINW - 1)) << 17) | (unsigned)c[i];
    }
}

// Fine partition: one block per bin; emits node-sorted cols_s + per-node offs.
__global__ __launch_bounds__(256) void k_part2(
    const unsigned* __restrict__ tmp, const int* __restrict__ binoffs,
    int* __restrict__ offs, int* __restrict__ cols_s) {
    __shared__ unsigned stage[CAP2];          // 48 KB
    __shared__ int h[BINW], ps[256], cur[BINW];
    const int b = blockIdx.x, t = threadIdx.x;
    const int node0 = b * BINW;
    const int gs = binoffs[b], ge = binoffs[b + 1];
    const int cnt = ge - gs;
    for (int i = t; i < BINW; i += 256) h[i] = 0;
    __syncthreads();
    for (int j = t; j < cnt; j += 256) {
        const unsigned p = tmp[gs + j];
        if (j < CAP2) stage[j] = p;
        atomicAdd(&h[p >> 17], 1);
    }
    __syncthreads();
    const int a0 = h[2 * t], a1 = h[2 * t + 1];
    ps[t] = a0 + a1;
    __syncthreads();
    for (int o = 1; o < 256; o <<= 1) {
        const int add = (t >= o) ? ps[t - o] : 0;
        __syncthreads();
        ps[t] += add;
        __syncthreads();
    }
    const int ex = ps[t] - a0 - a1 + gs;
    cur[2 * t] = ex;
    cur[2 * t + 1] = ex + a0;
    if (node0 + 2 * t < NN)     offs[node0 + 2 * t]     = ex;
    if (node0 + 2 * t + 1 < NN) offs[node0 + 2 * t + 1] = ex + a0;
    __syncthreads();
    for (int j = t; j < cnt; j += 256) {
        const unsigned p = (j < CAP2) ? stage[j] : tmp[gs + j];
        const int pos = atomicAdd(&cur[p >> 17], 1);
        cols_s[pos] = (int)(p & 0x1FFFFu);
    }
}

// Fused score + softmax + aggregation: 16-lane group per node.
// Hybrid: cols broadcast-loaded (lane-local h addresses); scoring split
// across lanes; weights exchanged via shfl off the address path.
__global__ __launch_bounds__(256) void k_agg(
    const int* __restrict__ offs, const int* __restrict__ cols_s,
    const float* __restrict__ al, const float* __restrict__ ar,
    const __hip_bfloat16* __restrict__ hb, float* __restrict__ out) {
    const int w = threadIdx.x >> 6;
    const int lane = threadIdx.x & 63;
    const int g = lane >> 4;            // node slot within wave
    const int sl = lane & 15;           // sublane within group
    const int node = blockIdx.x * 16 + w * 4 + g;
    if (node >= NN) return;

    const int start = offs[node];
    const int deg = offs[node + 1] - start;
    const int hsel = sl >> 2;           // head owning this lane's 8 dims
    const int je = sl >> 2;             // edge slot this lane scores
    const int sh = sl & 3;              // head this lane scores
    const int sbase = lane & 48;        // group base lane
    const float al_sh = al[node * NH + sh];
    const char* hrow = (const char*)hb + sl * 16;   // lane's 16B slice

    f32x2 a0 = {0.f, 0.f}, a1 = {0.f, 0.f}, a2 = {0.f, 0.f}, a3 = {0.f, 0.f};
    float ssum = 0.f;

    // over-reads (<=60B past segment end) land in cols_s/tmp buffers: safe.
    int4 cA = *(const int4*)(cols_s + start);
    int4 cB = *(const int4*)(cols_s + start + 4);

    for (int kk = 0; kk < deg; kk += 8) {
        const int rem = deg - kk;
        const int4 cA2 = *(const int4*)(cols_s + start + kk + 8);
        const int4 cB2 = *(const int4*)(cols_s + start + kk + 12);

        float wvA = 0.f, wvB = 0.f;
        if (je < rem) {
            const int c = sel4(cA, je);
            wvA = __expf(lrelu(al_sh + ar[c * NH + sh]));
        }
        if (je + 4 < rem) {
            const int c = sel4(cB, je);
            wvB = __expf(lrelu(al_sh + ar[c * NH + sh]));
        }

        int c_[8] = {cA.x, cA.y, cA.z, cA.w, cB.x, cB.y, cB.z, cB.w};
#pragma unroll
        for (int j = 0; j < 8; ++j)
            if (j >= rem) c_[j] = 0;

#pragma unroll
        for (int j = 0; j < 8; ++j) {
            const float wj = __shfl(j < 4 ? wvA : wvB, sbase + (j & 3) * 4 + hsel);
            const uint4 v = *(const uint4*)(hrow + (size_t)c_[j] * 256);
            a0 += wj * (f32x2){__uint_as_float(v.x << 16), __uint_as_float(v.x & 0xffff0000u)};
            a1 += wj * (f32x2){__uint_as_float(v.y << 16), __uint_as_float(v.y & 0xffff0000u)};
            a2 += wj * (f32x2){__uint_as_float(v.z << 16), __uint_as_float(v.z & 0xffff0000u)};
            a3 += wj * (f32x2){__uint_as_float(v.w << 16), __uint_as_float(v.w & 0xffff0000u)};
            ssum += wj;
        }
        cA = cA2; cB = cB2;
    }

    const float inv = (ssum > 0.f) ? 1.0f / ssum : 0.f;
    float4 o0, o1;
    o0.x = a0.x * inv; o0.y = a0.y * inv; o0.z = a1.x * inv; o0.w = a1.y * inv;
    o1.x = a2.x * inv; o1.y = a2.y * inv; o1.z = a3.x * inv; o1.w = a3.y * inv;
    float* dst = out + (size_t)node * OC + sl * 8;
    *(float4*)dst = o0;
    *(float4*)(dst + 4) = o1;
}

extern "C" void kernel_launch(void* const* d_in, const int* in_sizes, int n_in,
                              void* d_out, int out_size, void* d_ws, size_t ws_size,
                              hipStream_t stream) {
    const float* x    = (const float*)d_in[0];
    const int*   ei   = (const int*)d_in[1];    // [2, NE]
    const float* W    = (const float*)d_in[2];
    const float* a_l  = (const float*)d_in[3];
    const float* a_r  = (const float*)d_in[4];
    float* out = (float*)d_out;

    const int* row = ei;         // destination
    const int* col = ei + NE;    // source

    char* ws = (char*)d_ws;
    __hip_bfloat16* hb = (__hip_bfloat16*)ws;   ws += (size_t)NN * OC * 2;   // 25.6 MB
    __hip_bfloat16* Wt = (__hip_bfloat16*)ws;   ws += (size_t)INF_ * OC * 2; // 32 KB
    float*    al      = (float*)ws;             ws += (size_t)NN * NH * 4;
    float*    ar      = (float*)ws;             ws += (size_t)NN * NH * 4;
    int*      cols_s  = (int*)ws;               ws += (size_t)NE * 4;        // 6.4 MB
    unsigned* tmp     = (unsigned*)ws;          ws += (size_t)NE * 4;        // 6.4 MB
    int*      offs    = (int*)ws;               ws += (size_t)(NN + 1) * 4;
    int*      bincnt  = (int*)ws;               ws += (size_t)(NBIN + 1) * 4;
    int*      binoffs = (int*)ws;               ws += (size_t)(NBIN + 1) * 4;
    int*      bincur  = (int*)ws;               ws += (size_t)NBIN * 4;

    k_wconv<<<64, 256, 0, stream>>>(W, Wt, bincnt);
    k_gemm<<<(NN + 63) / 64, 256, 0, stream>>>(x, Wt, a_l, a_r, hb, al, ar, row, bincnt);
    k_binscan<<<1, 256, 0, stream>>>(bincnt, binoffs, bincur, offs);
    k_part1<<<NPB1, 256, 0, stream>>>(row, col, bincur, tmp);
    k_part2<<<NBIN, 256, 0, stream>>>(tmp, binoffs, offs, cols_s);
    k_agg<<<(NN + 15) / 16, 256, 0, stream>>>(offs, cols_s, al, ar, hb, out);
}

// Round 14
// 155.622 us; speedup vs baseline: 1.2350x; 1.0202x over previous
//
#include <hip/hip_runtime.h>
#include <hip/hip_bf16.h>
#include <string.h>

#define NN 100000
#define NE 1600000
#define INF_ 128
#define OC 128   // NHEAD*OUT_F
#define NH 4
#define ALPHA 0.2f
#define LDA 272                      // GEMM LDS row stride in bytes

#define BSH 9
#define BINW 512                     // nodes per bin
#define NBIN ((NN + BINW - 1) / BINW)   // 196
#define EPT 16                       // edges per thread, partition kernels
#define EPB (256 * EPT)              // 4096 edges per block
#define NPB1 ((NE + EPB - 1) / EPB)  // 391 blocks
#define CAP2 12288                   // LDS staging capacity in k_part2

typedef __bf16 bf16x8 __attribute__((ext_vector_type(8)));
typedef float f32x4 __attribute__((ext_vector_type(4)));
typedef float f32x2 __attribute__((ext_vector_type(2)));

__device__ __forceinline__ float lrelu(float x) {
    return x > 0.0f ? x : ALPHA * x;
}
__device__ __forceinline__ unsigned short f2bf(float f) {
    __hip_bfloat16 b = __float2bfloat16(f);
    unsigned short u; memcpy(&u, &b, 2); return u;
}
__device__ __forceinline__ int sel4(const int4 v, int j) {
    const int lo = (j & 1) ? v.y : v.x;
    const int hi = (j & 1) ? v.w : v.z;
    return (j & 2) ? hi : lo;
}

// Pre-pass: W transpose+convert (first 64 blocks) + per-block partial bin
// histograms (all NPB1 blocks, non-atomic global writes).
__global__ __launch_bounds__(256) void k_pre(
    const float* __restrict__ W, __hip_bfloat16* __restrict__ Wt,
    const int* __restrict__ row, int* __restrict__ partial) {
    __shared__ int hsh[NBIN];
    const int t = threadIdx.x;
    if (blockIdx.x < 64) {
        const int i = blockIdx.x * 256 + t;   // < 16384
        const int co = i >> 7, ko = i & 127;
        Wt[i] = __float2bfloat16(W[ko * OC + co]);
    }
    for (int i = t; i < NBIN; i += 256) hsh[i] = 0;
    __syncthreads();
    const int base = blockIdx.x * EPB;
    for (int i = 0; i < EPT; ++i) {
        const int e = base + t + i * 256;
        if (e < NE) atomicAdd(&hsh[row[e] >> BSH], 1);
    }
    __syncthreads();
    for (int i = t; i < NBIN; i += 256)
        partial[blockIdx.x * NBIN + i] = hsh[i];
}

// Sum partial histograms + exclusive scan -> binoffs, bincur; also offs[NN].
__global__ __launch_bounds__(256) void k_binscan(
    const int* __restrict__ partial, int* __restrict__ binoffs,
    int* __restrict__ bincur, int* __restrict__ offs) {
    __shared__ int ts[256];
    const int t = threadIdx.x;
    int v = 0;
    if (t < NBIN) {
#pragma unroll 8
        for (int i = 0; i < NPB1; ++i) v += partial[i * NBIN + t];
    }
    ts[t] = v;
    __syncthreads();
    for (int o = 1; o < 256; o <<= 1) {
        const int add = (t >= o) ? ts[t - o] : 0;
        __syncthreads();
        ts[t] += add;
        __syncthreads();
    }
    const int ex = ts[t] - v;
    if (t < NBIN) { binoffs[t] = ex; bincur[t] = ex; }
    if (t == 255) {
        binoffs[NBIN] = ts[255];   // == NE
        offs[NN] = NE;
    }
}

// Mega-kernel: gemm blocks (role %5 != 4) and part1 blocks (role %5 == 4)
// interleaved 4:1 so both phases run concurrently.
__global__ __launch_bounds__(256) void k_gp1(
    const float* __restrict__ x, const __hip_bfloat16* __restrict__ Wt,
    const float* __restrict__ a_l, const float* __restrict__ a_r,
    __hip_bfloat16* __restrict__ hb, float* __restrict__ al, float* __restrict__ ar,
    const int* __restrict__ row, const int* __restrict__ col,
    int* __restrict__ bincur, unsigned* __restrict__ tmp) {
    __shared__ __align__(16) char smem[128 * LDA];   // 34.8 KB, carved per role
    const int tid = threadIdx.x;
    const int m5 = blockIdx.x % 5;

    if (m5 != 4) {
        // ---- GEMM path: h = x @ W + fused al/ar epilogue ----
        char* sB = smem;                                  // Wt [col][k]
        const int gb = (blockIdx.x / 5) * 4 + m5;         // 0..1563 (1563 = spare)
        const int rowBase = gb * 64;

        for (int i4 = tid; i4 < 2048; i4 += 256) {
            const int c = i4 >> 4, k4 = i4 & 15;
            *(uint4*)(sB + c * LDA + k4 * 16) =
                *(const uint4*)((const char*)Wt + (size_t)c * 256 + k4 * 16);
        }
        __syncthreads();

        const int lane = tid & 63;
        const int w = tid >> 6;
        const int arow = w * 16 + (lane & 15);
        const int grow = rowBase + arow;
        const int growc = (grow < NN) ? grow : (NN - 1);
        const int koff8 = (lane >> 4) * 8;
        const int koff = (lane >> 4) * 16;

        f32x4 acc[8];
#pragma unroll
        for (int n = 0; n < 8; ++n) acc[n] = (f32x4){0.f, 0.f, 0.f, 0.f};

#pragma unroll
        for (int kk = 0; kk < 4; ++kk) {
            const float* xp = x + (size_t)growc * INF_ + kk * 32 + koff8;
            const float4 f0 = *(const float4*)xp;
            const float4 f1 = *(const float4*)(xp + 4);
            union { bf16x8 v; unsigned short u[8]; } au;
            au.u[0] = f2bf(f0.x); au.u[1] = f2bf(f0.y);
            au.u[2] = f2bf(f0.z); au.u[3] = f2bf(f0.w);
            au.u[4] = f2bf(f1.x); au.u[5] = f2bf(f1.y);
            au.u[6] = f2bf(f1.z); au.u[7] = f2bf(f1.w);
#pragma unroll
            for (int n = 0; n < 8; ++n) {
                const int brow = n * 16 + (lane & 15);
                const bf16x8 b = *(const bf16x8*)(sB + brow * LDA + kk * 64 + koff);
                acc[n] = __builtin_amdgcn_mfma_f32_16x16x32_bf16(au.v, b, acc[n], 0, 0, 0);
            }
        }

        const int rbase = rowBase + w * 16 + (lane >> 4) * 4;
#pragma unroll
        for (int n = 0; n < 8; ++n) {
            const int cc = n * 16 + (lane & 15);
#pragma unroll
            for (int r = 0; r < 4; ++r) {
                const int rw = rbase + r;
                if (rw < NN) hb[(size_t)rw * OC + cc] = __float2bfloat16(acc[n][r]);
            }
        }

        float alw[8], arw[8];
#pragma unroll
        for (int n = 0; n < 8; ++n) {
            alw[n] = a_l[n * 16 + (lane & 15)];
            arw[n] = a_r[n * 16 + (lane & 15)];
        }
#pragma unroll
        for (int r = 0; r < 4; ++r) {
            const int rw = rbase + r;
#pragma unroll
            for (int hd = 0; hd < 4; ++hd) {
                float pl = acc[2 * hd][r] * alw[2 * hd] + acc[2 * hd + 1][r] * alw[2 * hd + 1];
                float pr = acc[2 * hd][r] * arw[2 * hd] + acc[2 * hd + 1][r] * arw[2 * hd + 1];
#pragma unroll
                for (int m = 1; m <= 8; m <<= 1) {
                    pl += __shfl_xor(pl, m);
                    pr += __shfl_xor(pr, m);
                }
                if ((lane & 15) == hd && rw < NN) {
                    al[rw * NH + hd] = pl;
                    ar[rw * NH + hd] = pr;
                }
            }
        }
    } else {
        // ---- part1 path: coarse partition into bin-grouped packed words ----
        int* h     = (int*)smem;
        int* gbase = h + NBIN;
        int* lcur  = gbase + NBIN;
        const int pb = blockIdx.x / 5;    // 0..390
        const int t = tid;
        for (int i = t; i < NBIN; i += 256) { h[i] = 0; lcur[i] = 0; }
        __syncthreads();

        const int e0 = pb * EPB + t * EPT;
        int r[EPT], c[EPT];
        if (e0 + EPT <= NE) {
#pragma unroll
            for (int q = 0; q < EPT / 4; ++q) {
                const int4 rv = *(const int4*)&row[e0 + q * 4];
                const int4 cv = *(const int4*)&col[e0 + q * 4];
                r[q*4+0] = rv.x; r[q*4+1] = rv.y; r[q*4+2] = rv.z; r[q*4+3] = rv.w;
                c[q*4+0] = cv.x; c[q*4+1] = cv.y; c[q*4+2] = cv.z; c[q*4+3] = cv.w;
            }
        } else {
#pragma unroll
            for (int i = 0; i < EPT; ++i) {
                const int e = e0 + i;
                r[i] = (e < NE) ? row[e] : -1;
                c[i] = (e < NE) ? col[e] : 0;
            }
        }
#pragma unroll
        for (int i = 0; i < EPT; ++i)
            if (r[i] >= 0) atomicAdd(&h[r[i] >> BSH], 1);
        __syncthreads();
        for (int i = t; i < NBIN; i += 256)
            if (h[i]) gbase[i] = atomicAdd(&bincur[i], h[i]);
        __syncthreads();
#pragma unroll
        for (int i = 0; i < EPT; ++i) {
            if (r[i] < 0) continue;
            const int b = r[i] >> BSH;
            const int pos = atomicAdd(&lcur[b], 1);
            tmp[gbase[b] + pos] =
                ((unsigned)(r[i] & (BINW - 1)) << 17) | (unsigned)c[i];
        }
    }
}

// Fine partition: one block per bin; emits node-sorted cols_s + per-node offs.
__global__ __launch_bounds__(256) void k_part2(
    const unsigned* __restrict__ tmp, const int* __restrict__ binoffs,
    int* __restrict__ offs, int* __restrict__ cols_s) {
    __shared__ unsigned stage[CAP2];          // 48 KB
    __shared__ int h[BINW], ps[256], cur[BINW];
    const int b = blockIdx.x, t = threadIdx.x;
    const int node0 = b * BINW;
    const int gs = binoffs[b], ge = binoffs[b + 1];
    const int cnt = ge - gs;
    for (int i = t; i < BINW; i += 256) h[i] = 0;
    __syncthreads();
    for (int j = t; j < cnt; j += 256) {
        const unsigned p = tmp[gs + j];
        if (j < CAP2) stage[j] = p;
        atomicAdd(&h[p >> 17], 1);
    }
    __syncthreads();
    const int a0 = h[2 * t], a1 = h[2 * t + 1];
    ps[t] = a0 + a1;
    __syncthreads();
    for (int o = 1; o < 256; o <<= 1) {
        const int add = (t >= o) ? ps[t - o] : 0;
        __syncthreads();
        ps[t] += add;
        __syncthreads();
    }
    const int ex = ps[t] - a0 - a1 + gs;
    cur[2 * t] = ex;
    cur[2 * t + 1] = ex + a0;
    if (node0 + 2 * t < NN)     offs[node0 + 2 * t]     = ex;
    if (node0 + 2 * t + 1 < NN) offs[node0 + 2 * t + 1] = ex + a0;
    __syncthreads();
    for (int j = t; j < cnt; j += 256) {
        const unsigned p = (j < CAP2) ? stage[j] : tmp[gs + j];
        const int pos = atomicAdd(&cur[p >> 17], 1);
        cols_s[pos] = (int)(p & 0x1FFFFu);
    }
}

// Fused score + softmax + aggregation: 16-lane group per node.
// Hybrid: cols broadcast-loaded (lane-local h addresses); scoring split
// across lanes; weights exchanged via shfl off the address path.
__global__ __launch_bounds__(256) void k_agg(
    const int* __restrict__ offs, const int* __restrict__ cols_s,
    const float* __restrict__ al, const float* __restrict__ ar,
    const __hip_bfloat16* __restrict__ hb, float* __restrict__ out) {
    const int w = threadIdx.x >> 6;
    const int lane = threadIdx.x & 63;
    const int g = lane >> 4;            // node slot within wave
    const int sl = lane & 15;           // sublane within group
    const int node = blockIdx.x * 16 + w * 4 + g;
    if (node >= NN) return;

    const int start = offs[node];
    const int deg = offs[node + 1] - start;
    const int hsel = sl >> 2;           // head owning this lane's 8 dims
    const int je = sl >> 2;             // edge slot this lane scores
    const int sh = sl & 3;              // head this lane scores
    const int sbase = lane & 48;        // group base lane
    const float al_sh = al[node * NH + sh];
    const char* hrow = (const char*)hb + sl * 16;   // lane's 16B slice

    f32x2 a0 = {0.f, 0.f}, a1 = {0.f, 0.f}, a2 = {0.f, 0.f}, a3 = {0.f, 0.f};
    float ssum = 0.f;

    // over-reads (<=60B past segment end) land in cols_s/tmp buffers: safe.
    int4 cA = *(const int4*)(cols_s + start);
    int4 cB = *(const int4*)(cols_s + start + 4);

    for (int kk = 0; kk < deg; kk += 8) {
        const int rem = deg - kk;
        const int4 cA2 = *(const int4*)(cols_s + start + kk + 8);
        const int4 cB2 = *(const int4*)(cols_s + start + kk + 12);

        float wvA = 0.f, wvB = 0.f;
        if (je < rem) {
            const int c = sel4(cA, je);
            wvA = __expf(lrelu(al_sh + ar[c * NH + sh]));
        }
        if (je + 4 < rem) {
            const int c = sel4(cB, je);
            wvB = __expf(lrelu(al_sh + ar[c * NH + sh]));
        }

        int c_[8] = {cA.x, cA.y, cA.z, cA.w, cB.x, cB.y, cB.z, cB.w};
#pragma unroll
        for (int j = 0; j < 8; ++j)
            if (j >= rem) c_[j] = 0;

#pragma unroll
        for (int j = 0; j < 8; ++j) {
            const float wj = __shfl(j < 4 ? wvA : wvB, sbase + (j & 3) * 4 + hsel);
            const uint4 v = *(const uint4*)(hrow + (size_t)c_[j] * 256);
            a0 += wj * (f32x2){__uint_as_float(v.x << 16), __uint_as_float(v.x & 0xffff0000u)};
            a1 += wj * (f32x2){__uint_as_float(v.y << 16), __uint_as_float(v.y & 0xffff0000u)};
            a2 += wj * (f32x2){__uint_as_float(v.z << 16), __uint_as_float(v.z & 0xffff0000u)};
            a3 += wj * (f32x2){__uint_as_float(v.w << 16), __uint_as_float(v.w & 0xffff0000u)};
            ssum += wj;
        }
        cA = cA2; cB = cB2;
    }

    const float inv = (ssum > 0.f) ? 1.0f / ssum : 0.f;
    float4 o0, o1;
    o0.x = a0.x * inv; o0.y = a0.y * inv; o0.z = a1.x * inv; o0.w = a1.y * inv;
    o1.x = a2.x * inv; o1.y = a2.y * inv; o1.z = a3.x * inv; o1.w = a3.y * inv;
    float* dst = out + (size_t)node * OC + sl * 8;
    *(float4*)dst = o0;
    *(float4*)(dst + 4) = o1;
}

extern "C" void kernel_launch(void* const* d_in, const int* in_sizes, int n_in,
                              void* d_out, int out_size, void* d_ws, size_t ws_size,
                              hipStream_t stream) {
    const float* x    = (const float*)d_in[0];
    const int*   ei   = (const int*)d_in[1];    // [2, NE]
    const float* W    = (const float*)d_in[2];
    const float* a_l  = (const float*)d_in[3];
    const float* a_r  = (const float*)d_in[4];
    float* out = (float*)d_out;

    const int* row = ei;         // destination
    const int* col = ei + NE;    // source

    char* ws = (char*)d_ws;
    __hip_bfloat16* hb = (__hip_bfloat16*)ws;   ws += (size_t)NN * OC * 2;   // 25.6 MB
    __hip_bfloat16* Wt = (__hip_bfloat16*)ws;   ws += (size_t)INF_ * OC * 2; // 32 KB
    float*    al      = (float*)ws;             ws += (size_t)NN * NH * 4;
    float*    ar      = (float*)ws;             ws += (size_t)NN * NH * 4;
    int*      cols_s  = (int*)ws;               ws += (size_t)NE * 4;        // 6.4 MB
    unsigned* tmp     = (unsigned*)ws;          ws += (size_t)NE * 4;        // 6.4 MB
    int*      offs    = (int*)ws;               ws += (size_t)(NN + 1) * 4;
    int*      partial = (int*)ws;               ws += (size_t)NPB1 * NBIN * 4; // 306 KB
    int*      binoffs = (int*)ws;               ws += (size_t)(NBIN + 1) * 4;
    int*      bincur  = (int*)ws;               ws += (size_t)NBIN * 4;

    k_pre<<<NPB1, 256, 0, stream>>>(W, Wt, row, partial);
    k_binscan<<<1, 256, 0, stream>>>(partial, binoffs, bincur, offs);
    k_gp1<<<1955, 256, 0, stream>>>(x, Wt, a_l, a_r, hb, al, ar, row, col, bincur, tmp);
    k_part2<<<NBIN, 256, 0, stream>>>(tmp, binoffs, offs, cols_s);
    k_agg<<<(NN + 15) / 16, 256, 0, stream>>>(offs, cols_s, al, ar, hb, out);
}

// Round 15
// 133.398 us; speedup vs baseline: 1.4407x; 1.1666x over previous
//
#include <hip/hip_runtime.h>
#include <hip/hip_bf16.h>
#include <string.h>

#define NN 100000
#define NE 1600000
#define INF_ 128
#define OC 128   // NHEAD*OUT_F
#define NH 4
#define ALPHA 0.2f
#define LDA 272                      // GEMM LDS row stride in bytes

#define BSH 9
#define BINW 512                     // nodes per bin
#define NBIN ((NN + BINW - 1) / BINW)   // 196
#define CAPB 10240                  // padded per-bin capacity (mean 8163, sigma~90)
#define EPT 16                       // edges per thread, partition kernels
#define EPB (256 * EPT)              // 4096 edges per block
#define NPB1 ((NE + EPB - 1) / EPB)  // 391 blocks
#define CAP2 12288                   // LDS staging capacity in k_part2

typedef __bf16 bf16x8 __attribute__((ext_vector_type(8)));
typedef float f32x4 __attribute__((ext_vector_type(4)));
typedef float f32x2 __attribute__((ext_vector_type(2)));

__device__ __forceinline__ float lrelu(float x) {
    return x > 0.0f ? x : ALPHA * x;
}
__device__ __forceinline__ unsigned short f2bf(float f) {
    __hip_bfloat16 b = __float2bfloat16(f);
    unsigned short u; memcpy(&u, &b, 2); return u;
}
__device__ __forceinline__ int sel4(const int4 v, int j) {
    const int lo = (j & 1) ? v.y : v.x;
    const int hi = (j & 1) ? v.w : v.z;
    return (j & 2) ? hi : lo;
}

// Pre-pass: W transpose+convert (64 blocks); block 0 inits padded bin cursors.
__global__ __launch_bounds__(256) void k_pre(
    const float* __restrict__ W, __hip_bfloat16* __restrict__ Wt,
    int* __restrict__ bincur) {
    const int i = blockIdx.x * 256 + threadIdx.x;   // < 16384
    const int co = i >> 7, ko = i & 127;
    Wt[i] = __float2bfloat16(W[ko * OC + co]);
    if (blockIdx.x == 0 && threadIdx.x < NBIN)
        bincur[threadIdx.x] = threadIdx.x * CAPB;
}

// Mega-kernel: gemm blocks (role %5 != 4) and part1 blocks (role %5 == 4)
// interleaved 4:1 so both phases run concurrently.
__global__ __launch_bounds__(256) void k_gp1(
    const float* __restrict__ x, const __hip_bfloat16* __restrict__ Wt,
    const float* __restrict__ a_l, const float* __restrict__ a_r,
    __hip_bfloat16* __restrict__ hb, float* __restrict__ al, float* __restrict__ ar,
    const int* __restrict__ row, const int* __restrict__ col,
    int* __restrict__ bincur, unsigned* __restrict__ tmp) {
    __shared__ __align__(16) char smem[128 * LDA];   // 34.8 KB, carved per role
    const int tid = threadIdx.x;
    const int m5 = blockIdx.x % 5;

    if (m5 != 4) {
        // ---- GEMM path: h = x @ W + fused al/ar epilogue ----
        char* sB = smem;                                  // Wt [col][k]
        const int gb = (blockIdx.x / 5) * 4 + m5;         // 0..1563 (1563 = spare)
        const int rowBase = gb * 64;

        for (int i4 = tid; i4 < 2048; i4 += 256) {
            const int c = i4 >> 4, k4 = i4 & 15;
            *(uint4*)(sB + c * LDA + k4 * 16) =
                *(const uint4*)((const char*)Wt + (size_t)c * 256 + k4 * 16);
        }
        __syncthreads();

        const int lane = tid & 63;
        const int w = tid >> 6;
        const int arow = w * 16 + (lane & 15);
        const int grow = rowBase + arow;
        const int growc = (grow < NN) ? grow : (NN - 1);
        const int koff8 = (lane >> 4) * 8;
        const int koff = (lane >> 4) * 16;

        f32x4 acc[8];
#pragma unroll
        for (int n = 0; n < 8; ++n) acc[n] = (f32x4){0.f, 0.f, 0.f, 0.f};

#pragma unroll
        for (int kk = 0; kk < 4; ++kk) {
            const float* xp = x + (size_t)growc * INF_ + kk * 32 + koff8;
            const float4 f0 = *(const float4*)xp;
            const float4 f1 = *(const float4*)(xp + 4);
            union { bf16x8 v; unsigned short u[8]; } au;
            au.u[0] = f2bf(f0.x); au.u[1] = f2bf(f0.y);
            au.u[2] = f2bf(f0.z); au.u[3] = f2bf(f0.w);
            au.u[4] = f2bf(f1.x); au.u[5] = f2bf(f1.y);
            au.u[6] = f2bf(f1.z); au.u[7] = f2bf(f1.w);
#pragma unroll
            for (int n = 0; n < 8; ++n) {
                const int brow = n * 16 + (lane & 15);
                const bf16x8 b = *(const bf16x8*)(sB + brow * LDA + kk * 64 + koff);
                acc[n] = __builtin_amdgcn_mfma_f32_16x16x32_bf16(au.v, b, acc[n], 0, 0, 0);
            }
        }

        const int rbase = rowBase + w * 16 + (lane >> 4) * 4;
#pragma unroll
        for (int n = 0; n < 8; ++n) {
            const int cc = n * 16 + (lane & 15);
#pragma unroll
            for (int r = 0; r < 4; ++r) {
                const int rw = rbase + r;
                if (rw < NN) hb[(size_t)rw * OC + cc] = __float2bfloat16(acc[n][r]);
            }
        }

        float alw[8], arw[8];
#pragma unroll
        for (int n = 0; n < 8; ++n) {
            alw[n] = a_l[n * 16 + (lane & 15)];
            arw[n] = a_r[n * 16 + (lane & 15)];
        }
#pragma unroll
        for (int r = 0; r < 4; ++r) {
            const int rw = rbase + r;
#pragma unroll
            for (int hd = 0; hd < 4; ++hd) {
                float pl = acc[2 * hd][r] * alw[2 * hd] + acc[2 * hd + 1][r] * alw[2 * hd + 1];
                float pr = acc[2 * hd][r] * arw[2 * hd] + acc[2 * hd + 1][r] * arw[2 * hd + 1];
#pragma unroll
                for (int m = 1; m <= 8; m <<= 1) {
                    pl += __shfl_xor(pl, m);
                    pr += __shfl_xor(pr, m);
                }
                if ((lane & 15) == hd && rw < NN) {
                    al[rw * NH + hd] = pl;
                    ar[rw * NH + hd] = pr;
                }
            }
        }
    } else {
        // ---- part1 path: coarse partition into bin-grouped packed words ----
        int* h     = (int*)smem;
        int* gbase = h + NBIN;
        int* lcur  = gbase + NBIN;
        const int pb = blockIdx.x / 5;    // 0..390
        const int t = tid;
        for (int i = t; i < NBIN; i += 256) { h[i] = 0; lcur[i] = 0; }
        __syncthreads();

        const int e0 = pb * EPB + t * EPT;
        int r[EPT], c[EPT];
        if (e0 + EPT <= NE) {
#pragma unroll
            for (int q = 0; q < EPT / 4; ++q) {
                const int4 rv = *(const int4*)&row[e0 + q * 4];
                const int4 cv = *(const int4*)&col[e0 + q * 4];
                r[q*4+0] = rv.x; r[q*4+1] = rv.y; r[q*4+2] = rv.z; r[q*4+3] = rv.w;
                c[q*4+0] = cv.x; c[q*4+1] = cv.y; c[q*4+2] = cv.z; c[q*4+3] = cv.w;
            }
        } else {
#pragma unroll
            for (int i = 0; i < EPT; ++i) {
                const int e = e0 + i;
                r[i] = (e < NE) ? row[e] : -1;
                c[i] = (e < NE) ? col[e] : 0;
            }
        }
#pragma unroll
        for (int i = 0; i < EPT; ++i)
            if (r[i] >= 0) atomicAdd(&h[r[i] >> BSH], 1);
        __syncthreads();
        for (int i = t; i < NBIN; i += 256)
            if (h[i]) gbase[i] = atomicAdd(&bincur[i], h[i]);
        __syncthreads();
#pragma unroll
        for (int i = 0; i < EPT; ++i) {
            if (r[i] < 0) continue;
            const int b = r[i] >> BSH;
            const int pos = atomicAdd(&lcur[b], 1);
            tmp[gbase[b] + pos] =
                ((unsigned)(r[i] & (BINW - 1)) << 17) | (unsigned)c[i];
        }
    }
}

// Fine partition: one block per bin; emits node-sorted cols_s + per-node
// (start,deg) info. Bin b owns cols_s[b*CAPB ..).
__global__ __launch_bounds__(256) void k_part2(
    const unsigned* __restrict__ tmp, const int* __restrict__ bincur,
    int2* __restrict__ nodeinfo, int* __restrict__ cols_s) {
    __shared__ unsigned stage[CAP2];          // 48 KB
    __shared__ int h[BINW], ps[256], cur[BINW];
    const int b = blockIdx.x, t = threadIdx.x;
    const int node0 = b * BINW;
    const int gs = b * CAPB;
    const int cnt = bincur[b] - gs;
    for (int i = t; i < BINW; i += 256) h[i] = 0;
    __syncthreads();
    for (int j = t; j < cnt; j += 256) {
        const unsigned p = tmp[gs + j];
        if (j < CAP2) stage[j] = p;
        atomicAdd(&h[p >> 17], 1);
    }
    __syncthreads();
    const int a0 = h[2 * t], a1 = h[2 * t + 1];
    ps[t] = a0 + a1;
    __syncthreads();
    for (int o = 1; o < 256; o <<= 1) {
        const int add = (t >= o) ? ps[t - o] : 0;
        __syncthreads();
        ps[t] += add;
        __syncthreads();
    }
    const int ex = ps[t] - a0 - a1 + gs;
    cur[2 * t] = ex;
    cur[2 * t + 1] = ex + a0;
    if (node0 + 2 * t < NN)     nodeinfo[node0 + 2 * t]     = make_int2(ex, a0);
    if (node0 + 2 * t + 1 < NN) nodeinfo[node0 + 2 * t + 1] = make_int2(ex + a0, a1);
    __syncthreads();
    for (int j = t; j < cnt; j += 256) {
        const unsigned p = (j < CAP2) ? stage[j] : tmp[gs + j];
        const int pos = atomicAdd(&cur[p >> 17], 1);
        cols_s[pos] = (int)(p & 0x1FFFFu);
    }
}

// Fused score + softmax + aggregation: 16-lane group per node.
// Hybrid: cols broadcast-loaded (lane-local h addresses); scoring split
// across lanes; weights exchanged via shfl off the address path.
__global__ __launch_bounds__(256) void k_agg(
    const int2* __restrict__ nodeinfo, const int* __restrict__ cols_s,
    const float* __restrict__ al, const float* __restrict__ ar,
    const __hip_bfloat16* __restrict__ hb, float* __restrict__ out) {
    const int w = threadIdx.x >> 6;
    const int lane = threadIdx.x & 63;
    const int g = lane >> 4;            // node slot within wave
    const int sl = lane & 15;           // sublane within group
    const int node = blockIdx.x * 16 + w * 4 + g;
    if (node >= NN) return;

    const int2 info = nodeinfo[node];
    const int start = info.x;
    const int deg = info.y;
    const int hsel = sl >> 2;           // head owning this lane's 8 dims
    const int je = sl >> 2;             // edge slot this lane scores
    const int sh = sl & 3;              // head this lane scores
    const int sbase = lane & 48;        // group base lane
    const float al_sh = al[node * NH + sh];
    const char* hrow = (const char*)hb + sl * 16;   // lane's 16B slice

    f32x2 a0 = {0.f, 0.f}, a1 = {0.f, 0.f}, a2 = {0.f, 0.f}, a3 = {0.f, 0.f};
    float ssum = 0.f;

    // over-reads (<=60B past segment end) stay inside the padded bin: safe.
    int4 cA = *(const int4*)(cols_s + start);
    int4 cB = *(const int4*)(cols_s + start + 4);

    for (int kk = 0; kk < deg; kk += 8) {
        const int rem = deg - kk;
        const int4 cA2 = *(const int4*)(cols_s + start + kk + 8);
        const int4 cB2 = *(const int4*)(cols_s + start + kk + 12);

        float wvA = 0.f, wvB = 0.f;
        if (je < rem) {
            const int c = sel4(cA, je);
            wvA = __expf(lrelu(al_sh + ar[c * NH + sh]));
        }
        if (je + 4 < rem) {
            const int c = sel4(cB, je);
            wvB = __expf(lrelu(al_sh + ar[c * NH + sh]));
        }

        int c_[8] = {cA.x, cA.y, cA.z, cA.w, cB.x, cB.y, cB.z, cB.w};
#pragma unroll
        for (int j = 0; j < 8; ++j)
            if (j >= rem) c_[j] = 0;

#pragma unroll
        for (int j = 0; j < 8; ++j) {
            const float wj = __shfl(j < 4 ? wvA : wvB, sbase + (j & 3) * 4 + hsel);
            const uint4 v = *(const uint4*)(hrow + (size_t)c_[j] * 256);
            a0 += wj * (f32x2){__uint_as_float(v.x << 16), __uint_as_float(v.x & 0xffff0000u)};
            a1 += wj * (f32x2){__uint_as_float(v.y << 16), __uint_as_float(v.y & 0xffff0000u)};
            a2 += wj * (f32x2){__uint_as_float(v.z << 16), __uint_as_float(v.z & 0xffff0000u)};
            a3 += wj * (f32x2){__uint_as_float(v.w << 16), __uint_as_float(v.w & 0xffff0000u)};
            ssum += wj;
        }
        cA = cA2; cB = cB2;
    }

    const float inv = (ssum > 0.f) ? 1.0f / ssum : 0.f;
    float4 o0, o1;
    o0.x = a0.x * inv; o0.y = a0.y * inv; o0.z = a1.x * inv; o0.w = a1.y * inv;
    o1.x = a2.x * inv; o1.y = a2.y * inv; o1.z = a3.x * inv; o1.w = a3.y * inv;
    float* dst = out + (size_t)node * OC + sl * 8;
    *(float4*)dst = o0;
    *(float4*)(dst + 4) = o1;
}

extern "C" void kernel_launch(void* const* d_in, const int* in_sizes, int n_in,
                              void* d_out, int out_size, void* d_ws, size_t ws_size,
                              hipStream_t stream) {
    const float* x    = (const float*)d_in[0];
    const int*   ei   = (const int*)d_in[1];    // [2, NE]
    const float* W    = (const float*)d_in[2];
    const float* a_l  = (const float*)d_in[3];
    const float* a_r  = (const float*)d_in[4];
    float* out = (float*)d_out;

    const int* row = ei;         // destination
    const int* col = ei + NE;    // source

    char* ws = (char*)d_ws;
    __hip_bfloat16* hb = (__hip_bfloat16*)ws;   ws += (size_t)NN * OC * 2;      // 25.6 MB
    __hip_bfloat16* Wt = (__hip_bfloat16*)ws;   ws += (size_t)INF_ * OC * 2;    // 32 KB
    float*    al      = (float*)ws;             ws += (size_t)NN * NH * 4;
    float*    ar      = (float*)ws;             ws += (size_t)NN * NH * 4;
    int*      cols_s  = (int*)ws;               ws += (size_t)NBIN * CAPB * 4;  // 8.0 MB
    unsigned* tmp     = (unsigned*)ws;          ws += (size_t)NBIN * CAPB * 4;  // 8.0 MB
    int2*     nodeinfo= (int2*)ws;              ws += (size_t)NN * 8;           // 800 KB
    int*      bincur  = (int*)ws;               ws += (size_t)NBIN * 4;

    k_pre<<<64, 256, 0, stream>>>(W, Wt, bincur);
    k_gp1<<<1955, 256, 0, stream>>>(x, Wt, a_l, a_r, hb, al, ar, row, col, bincur, tmp);
    k_part2<<<NBIN, 256, 0, stream>>>(tmp, bincur, nodeinfo, cols_s);
    k_agg<<<(NN + 15) / 16, 256, 0, stream>>>(nodeinfo, cols_s, al, ar, hb, out);
}

// Round 16
// 125.301 us; speedup vs baseline: 1.5338x; 1.0646x over previous
//
#include <hip/hip_runtime.h>
#include <hip/hip_bf16.h>
#include <string.h>

#define NN 100000
#define NE 1600000
#define INF_ 128
#define OC 128   // NHEAD*OUT_F
#define NH 4
#define ALPHA 0.2f
#define LDA 272                      // GEMM LDS row stride in bytes

#define BSH 8
#define BINW 256                     // nodes per bin
#define NBIN ((NN + BINW - 1) / BINW)   // 392
#define CAPB 5120                    // padded per-bin capacity (mean 4081, sigma~64)
#define EPT 16                       // edges per thread, partition kernels
#define EPB (256 * EPT)              // 4096 edges per block
#define NPB1 ((NE + EPB - 1) / EPB)  // 391 blocks
#define CAP2B 6144                   // LDS staging capacity in k_part2

typedef __bf16 bf16x8 __attribute__((ext_vector_type(8)));
typedef float f32x4 __attribute__((ext_vector_type(4)));
typedef float f32x2 __attribute__((ext_vector_type(2)));

__device__ __forceinline__ float lrelu(float x) {
    return x > 0.0f ? x : ALPHA * x;
}
__device__ __forceinline__ unsigned short f2bf(float f) {
    __hip_bfloat16 b = __float2bfloat16(f);
    unsigned short u; memcpy(&u, &b, 2); return u;
}
__device__ __forceinline__ int sel4(const int4 v, int j) {
    const int lo = (j & 1) ? v.y : v.x;
    const int hi = (j & 1) ? v.w : v.z;
    return (j & 2) ? hi : lo;
}

// Pre-pass (72 blocks): blocks 0-63 transpose+convert W -> Wt[col][k];
// blocks 64-71 build the 16 extra B-columns: cols 128..131 = wl (per-head
// W·a_l fold), 132..135 = wr, 136..143 = zero. Block 0 inits bin cursors.
__global__ __launch_bounds__(256) void k_pre(
    const float* __restrict__ W, const float* __restrict__ a_l,
    const float* __restrict__ a_r, __hip_bfloat16* __restrict__ Wt,
    int* __restrict__ bincur) {
    const int t = threadIdx.x;
    const int b = blockIdx.x;
    if (b < 64) {
        const int i = b * 256 + t;            // < 16384
        const int co = i >> 7, ko = i & 127;
        Wt[i] = __float2bfloat16(W[ko * OC + co]);
    } else {
        const int i = (b - 64) * 256 + t;     // < 2048
        const int cp = i >> 7, k = i & 127;   // cp 0..15
        float v = 0.f;
        if (cp < 8) {
            const int hd = cp & 3;
            const float* av = (cp < 4) ? a_l : a_r;
#pragma unroll 8
            for (int j = 0; j < 32; ++j)
                v += W[k * OC + hd * 32 + j] * av[hd * 32 + j];
        }
        Wt[(128 + cp) * 128 + k] = __float2bfloat16(v);
    }
    if (b == 0)
        for (int i = t; i < NBIN; i += 256) bincur[i] = i * CAPB;
}

// Mega-kernel: gemm blocks (role %5 != 4) and part1 blocks (role %5 == 4).
__global__ __launch_bounds__(256) void k_gp1(
    const float* __restrict__ x, const __hip_bfloat16* __restrict__ Wt,
    __hip_bfloat16* __restrict__ hb, float* __restrict__ al, float* __restrict__ ar,
    const int* __restrict__ row, const int* __restrict__ col,
    int* __restrict__ bincur, unsigned* __restrict__ tmp) {
    __shared__ __align__(16) char smem[144 * LDA];   // 38.3 KB, carved per role
    const int tid = threadIdx.x;
    const int m5 = blockIdx.x % 5;

    if (m5 != 4) {
        // ---- GEMM path: [h | al | ar] = x @ [W | wl | wr] ----
        char* sB = smem;                                  // Wt [col][k], 144 rows
        const int gb = (blockIdx.x / 5) * 4 + m5;         // 0..1563 (1563 = spare)
        const int rowBase = gb * 64;

        for (int i4 = tid; i4 < 144 * 16; i4 += 256) {
            const int c = i4 >> 4, k4 = i4 & 15;
            *(uint4*)(sB + c * LDA + k4 * 16) =
                *(const uint4*)((const char*)Wt + (size_t)c * 256 + k4 * 16);
        }
        __syncthreads();

        const int lane = tid & 63;
        const int w = tid >> 6;
        const int arow = w * 16 + (lane & 15);
        const int grow = rowBase + arow;
        const int growc = (grow < NN) ? grow : (NN - 1);
        const int koff8 = (lane >> 4) * 8;
        const int koff = (lane >> 4) * 16;

        f32x4 acc[9];
#pragma unroll
        for (int n = 0; n < 9; ++n) acc[n] = (f32x4){0.f, 0.f, 0.f, 0.f};

#pragma unroll
        for (int kk = 0; kk < 4; ++kk) {
            const float* xp = x + (size_t)growc * INF_ + kk * 32 + koff8;
            const float4 f0 = *(const float4*)xp;
            const float4 f1 = *(const float4*)(xp + 4);
            union { bf16x8 v; unsigned short u[8]; } au;
            au.u[0] = f2bf(f0.x); au.u[1] = f2bf(f0.y);
            au.u[2] = f2bf(f0.z); au.u[3] = f2bf(f0.w);
            au.u[4] = f2bf(f1.x); au.u[5] = f2bf(f1.y);
            au.u[6] = f2bf(f1.z); au.u[7] = f2bf(f1.w);
#pragma unroll
            for (int n = 0; n < 9; ++n) {
                const int brow = n * 16 + (lane & 15);
                const bf16x8 b = *(const bf16x8*)(sB + brow * LDA + kk * 64 + koff);
                acc[n] = __builtin_amdgcn_mfma_f32_16x16x32_bf16(au.v, b, acc[n], 0, 0, 0);
            }
        }

        const int rbase = rowBase + w * 16 + (lane >> 4) * 4;
#pragma unroll
        for (int n = 0; n < 8; ++n) {
            const int cc = n * 16 + (lane & 15);
#pragma unroll
            for (int r = 0; r < 4; ++r) {
                const int rw = rbase + r;
                if (rw < NN) hb[(size_t)rw * OC + cc] = __float2bfloat16(acc[n][r]);
            }
        }
        // al/ar from fragment 8: col 128+cp; cp<4 -> al head cp, cp in 4..7 -> ar.
        const int cp = lane & 15;
        if (cp < 8) {
            const int hd = cp & 3;
            float* dst = (cp < 4) ? al : ar;
#pragma unroll
            for (int r = 0; r < 4; ++r) {
                const int rw = rbase + r;
                if (rw < NN) dst[rw * NH + hd] = acc[8][r];
            }
        }
    } else {
        // ---- part1 path: coarse partition into bin-grouped packed words ----
        int* h     = (int*)smem;
        int* gbase = h + NBIN;
        int* lcur  = gbase + NBIN;
        const int pb = blockIdx.x / 5;    // 0..390
        const int t = tid;
        for (int i = t; i < NBIN; i += 256) { h[i] = 0; lcur[i] = 0; }
        __syncthreads();

        const int e0 = pb * EPB + t * EPT;
        int r[EPT], c[EPT];
        if (e0 + EPT <= NE) {
#pragma unroll
            for (int q = 0; q < EPT / 4; ++q) {
                const int4 rv = *(const int4*)&row[e0 + q * 4];
                const int4 cv = *(const int4*)&col[e0 + q * 4];
                r[q*4+0] = rv.x; r[q*4+1] = rv.y; r[q*4+2] = rv.z; r[q*4+3] = rv.w;
                c[q*4+0] = cv.x; c[q*4+1] = cv.y; c[q*4+2] = cv.z; c[q*4+3] = cv.w;
            }
        } else {
#pragma unroll
            for (int i = 0; i < EPT; ++i) {
                const int e = e0 + i;
                r[i] = (e < NE) ? row[e] : -1;
                c[i] = (e < NE) ? col[e] : 0;
            }
        }
#pragma unroll
        for (int i = 0; i < EPT; ++i)
            if (r[i] >= 0) atomicAdd(&h[r[i] >> BSH], 1);
        __syncthreads();
        for (int i = t; i < NBIN; i += 256)
            if (h[i]) gbase[i] = atomicAdd(&bincur[i], h[i]);
        __syncthreads();
#pragma unroll
        for (int i = 0; i < EPT; ++i) {
            if (r[i] < 0) continue;
            const int b = r[i] >> BSH;
            const int pos = atomicAdd(&lcur[b], 1);
            tmp[gbase[b] + pos] =
                ((unsigned)(r[i] & (BINW - 1)) << 17) | (unsigned)c[i];
        }
    }
}

// Fine partition: one block per bin (256 nodes); emits node-sorted cols_s +
// per-node (start,deg). Bin b owns cols_s[b*CAPB ..).
__global__ __launch_bounds__(256) void k_part2(
    const unsigned* __restrict__ tmp, const int* __restrict__ bincur,
    int2* __restrict__ nodeinfo, int* __restrict__ cols_s) {
    __shared__ unsigned stage[CAP2B];         // 24 KB
    __shared__ int h[BINW], ts[256], cur[BINW];
    const int b = blockIdx.x, t = threadIdx.x;
    const int node0 = b * BINW;
    const int gs = b * CAPB;
    const int cnt = bincur[b] - gs;
    h[t] = 0;
    __syncthreads();
    for (int j = t; j < cnt; j += 256) {
        const unsigned p = tmp[gs + j];
        if (j < CAP2B) stage[j] = p;
        atomicAdd(&h[p >> 17], 1);
    }
    __syncthreads();
    const int v = h[t];
    ts[t] = v;
    __syncthreads();
    for (int o = 1; o < 256; o <<= 1) {
        const int add = (t >= o) ? ts[t - o] : 0;
        __syncthreads();
        ts[t] += add;
        __syncthreads();
    }
    const int ex = ts[t] - v + gs;
    cur[t] = ex;
    if (node0 + t < NN) nodeinfo[node0 + t] = make_int2(ex, v);
    __syncthreads();
    for (int j = t; j < cnt; j += 256) {
        const unsigned p = (j < CAP2B) ? stage[j] : tmp[gs + j];
        const int pos = atomicAdd(&cur[p >> 17], 1);
        cols_s[pos] = (int)(p & 0x1FFFFu);
    }
}

// Fused score + softmax + aggregation: 16-lane group per node.
__global__ __launch_bounds__(256) void k_agg(
    const int2* __restrict__ nodeinfo, const int* __restrict__ cols_s,
    const float* __restrict__ al, const float* __restrict__ ar,
    const __hip_bfloat16* __restrict__ hb, float* __restrict__ out) {
    const int w = threadIdx.x >> 6;
    const int lane = threadIdx.x & 63;
    const int g = lane >> 4;            // node slot within wave
    const int sl = lane & 15;           // sublane within group
    const int node = blockIdx.x * 16 + w * 4 + g;
    if (node >= NN) return;

    const int2 info = nodeinfo[node];
    const int start = info.x;
    const int deg = info.y;
    const int hsel = sl >> 2;           // head owning this lane's 8 dims
    const int je = sl >> 2;             // edge slot this lane scores
    const int sh = sl & 3;              // head this lane scores
    const int sbase = lane & 48;        // group base lane
    const float al_sh = al[node * NH + sh];
    const char* hrow = (const char*)hb + sl * 16;   // lane's 16B slice

    f32x2 a0 = {0.f, 0.f}, a1 = {0.f, 0.f}, a2 = {0.f, 0.f}, a3 = {0.f, 0.f};
    float ssum = 0.f;

    // over-reads (<=60B past segment end) stay inside the padded bin: safe.
    int4 cA = *(const int4*)(cols_s + start);
    int4 cB = *(const int4*)(cols_s + start + 4);

    for (int kk = 0; kk < deg; kk += 8) {
        const int rem = deg - kk;
        const int4 cA2 = *(const int4*)(cols_s + start + kk + 8);
        const int4 cB2 = *(const int4*)(cols_s + start + kk + 12);

        float wvA = 0.f, wvB = 0.f;
        if (je < rem) {
            const int c = sel4(cA, je);
            wvA = __expf(lrelu(al_sh + ar[c * NH + sh]));
        }
        if (je + 4 < rem) {
            const int c = sel4(cB, je);
            wvB = __expf(lrelu(al_sh + ar[c * NH + sh]));
        }

        int c_[8] = {cA.x, cA.y, cA.z, cA.w, cB.x, cB.y, cB.z, cB.w};
#pragma unroll
        for (int j = 0; j < 8; ++j)
            if (j >= rem) c_[j] = 0;

#pragma unroll
        for (int j = 0; j < 8; ++j) {
            const float wj = __shfl(j < 4 ? wvA : wvB, sbase + (j & 3) * 4 + hsel);
            const uint4 v = *(const uint4*)(hrow + (size_t)c_[j] * 256);
            a0 += wj * (f32x2){__uint_as_float(v.x << 16), __uint_as_float(v.x & 0xffff0000u)};
            a1 += wj * (f32x2){__uint_as_float(v.y << 16), __uint_as_float(v.y & 0xffff0000u)};
            a2 += wj * (f32x2){__uint_as_float(v.z << 16), __uint_as_float(v.z & 0xffff0000u)};
            a3 += wj * (f32x2){__uint_as_float(v.w << 16), __uint_as_float(v.w & 0xffff0000u)};
            ssum += wj;
        }
        cA = cA2; cB = cB2;
    }

    const float inv = (ssum > 0.f) ? 1.0f / ssum : 0.f;
    float4 o0, o1;
    o0.x = a0.x * inv; o0.y = a0.y * inv; o0.z = a1.x * inv; o0.w = a1.y * inv;
    o1.x = a2.x * inv; o1.y = a2.y * inv; o1.z = a3.x * inv; o1.w = a3.y * inv;
    float* dst = out + (size_t)node * OC + sl * 8;
    *(float4*)dst = o0;
    *(float4*)(dst + 4) = o1;
}

extern "C" void kernel_launch(void* const* d_in, const int* in_sizes, int n_in,
                              void* d_out, int out_size, void* d_ws, size_t ws_size,
                              hipStream_t stream) {
    const float* x    = (const float*)d_in[0];
    const int*   ei   = (const int*)d_in[1];    // [2, NE]
    const float* W    = (const float*)d_in[2];
    const float* a_l  = (const float*)d_in[3];
    const float* a_r  = (const float*)d_in[4];
    float* out = (float*)d_out;

    const int* row = ei;         // destination
    const int* col = ei + NE;    // source

    char* ws = (char*)d_ws;
    __hip_bfloat16* hb = (__hip_bfloat16*)ws;   ws += (size_t)NN * OC * 2;      // 25.6 MB
    __hip_bfloat16* Wt = (__hip_bfloat16*)ws;   ws += (size_t)144 * 128 * 2;    // 36 KB
    float*    al      = (float*)ws;             ws += (size_t)NN * NH * 4;
    float*    ar      = (float*)ws;             ws += (size_t)NN * NH * 4;
    int*      cols_s  = (int*)ws;               ws += (size_t)NBIN * CAPB * 4;  // 8.0 MB
    unsigned* tmp     = (unsigned*)ws;          ws += (size_t)NBIN * CAPB * 4;  // 8.0 MB
    int2*     nodeinfo= (int2*)ws;              ws += (size_t)NN * 8;           // 800 KB
    int*      bincur  = (int*)ws;               ws += (size_t)NBIN * 4;

    k_pre<<<72, 256, 0, stream>>>(W, a_l, a_r, Wt, bincur);
    k_gp1<<<1955, 256, 0, stream>>>(x, Wt, hb, al, ar, row, col, bincur, tmp);
    k_part2<<<NBIN, 256, 0, stream>>>(tmp, bincur, nodeinfo, cols_s);
    k_agg<<<(NN + 15) / 16, 256, 0, stream>>>(nodeinfo, cols_s, al, ar, hb, out);
}

// Round 17
// 123.440 us; speedup vs baseline: 1.5569x; 1.0151x over previous
//
#include <hip/hip_runtime.h>
#include <hip/hip_bf16.h>
#include <string.h>

#define NN 100000
#define NE 1600000
#define INF_ 128
#define OC 128   // NHEAD*OUT_F
#define NH 4
#define ALPHA 0.2f
#define LDA 272                      // GEMM LDS row stride in bytes

#define BSH 7
#define BINW 128                     // nodes per bin
#define NBIN ((NN + BINW - 1) / BINW)   // 782
#define CAPB 2560                    // padded per-bin capacity (mean 2046, sigma~45)
#define SCOLS_CAP (CAPB + 3 * BINW / 2 + 16)  // aligned-start fill + overhang
#define EPT 16                       // edges per thread, partition kernels
#define EPB (256 * EPT)              // 4096 edges per block
#define NPB1 ((NE + EPB - 1) / EPB)  // 391 blocks

typedef __bf16 bf16x8 __attribute__((ext_vector_type(8)));
typedef float f32x4 __attribute__((ext_vector_type(4)));
typedef float f32x2 __attribute__((ext_vector_type(2)));

__device__ __forceinline__ float lrelu(float x) {
    return x > 0.0f ? x : ALPHA * x;
}
__device__ __forceinline__ unsigned short f2bf(float f) {
    __hip_bfloat16 b = __float2bfloat16(f);
    unsigned short u; memcpy(&u, &b, 2); return u;
}
__device__ __forceinline__ int sel4(const int4 v, int j) {
    const int lo = (j & 1) ? v.y : v.x;
    const int hi = (j & 1) ? v.w : v.z;
    return (j & 2) ? hi : lo;
}

// Pre-pass (72 blocks): blocks 0-63 transpose+convert W -> Wt[col][k];
// blocks 64-71 build extra B-columns 128..135 = wl|wr folds, 136..143 zero.
// Block 0 inits padded bin cursors.
__global__ __launch_bounds__(256) void k_pre(
    const float* __restrict__ W, const float* __restrict__ a_l,
    const float* __restrict__ a_r, __hip_bfloat16* __restrict__ Wt,
    int* __restrict__ bincur) {
    const int t = threadIdx.x;
    const int b = blockIdx.x;
    if (b < 64) {
        const int i = b * 256 + t;            // < 16384
        const int co = i >> 7, ko = i & 127;
        Wt[i] = __float2bfloat16(W[ko * OC + co]);
    } else {
        const int i = (b - 64) * 256 + t;     // < 2048
        const int cp = i >> 7, k = i & 127;   // cp 0..15
        float v = 0.f;
        if (cp < 8) {
            const int hd = cp & 3;
            const float* av = (cp < 4) ? a_l : a_r;
#pragma unroll 8
            for (int j = 0; j < 32; ++j)
                v += W[k * OC + hd * 32 + j] * av[hd * 32 + j];
        }
        Wt[(128 + cp) * 128 + k] = __float2bfloat16(v);
    }
    if (b == 0)
        for (int i = t; i < NBIN; i += 256) bincur[i] = i * CAPB;
}

// Mega-kernel: gemm blocks (role %5 != 4) and part1 blocks (role %5 == 4).
__global__ __launch_bounds__(256) void k_gp1(
    const float* __restrict__ x, const __hip_bfloat16* __restrict__ Wt,
    __hip_bfloat16* __restrict__ hb, float* __restrict__ al, float* __restrict__ ar,
    const int* __restrict__ row, const int* __restrict__ col,
    int* __restrict__ bincur, unsigned* __restrict__ tmp) {
    __shared__ __align__(16) char smem[144 * LDA];   // 38.3 KB, carved per role
    const int tid = threadIdx.x;
    const int m5 = blockIdx.x % 5;

    if (m5 != 4) {
        // ---- GEMM path: [h | al | ar] = x @ [W | wl | wr] ----
        char* sB = smem;                                  // Wt [col][k], 144 rows
        const int gb = (blockIdx.x / 5) * 4 + m5;         // 0..1563 (1563 = spare)
        const int rowBase = gb * 64;

        for (int i4 = tid; i4 < 144 * 16; i4 += 256) {
            const int c = i4 >> 4, k4 = i4 & 15;
            *(uint4*)(sB + c * LDA + k4 * 16) =
                *(const uint4*)((const char*)Wt + (size_t)c * 256 + k4 * 16);
        }
        __syncthreads();

        const int lane = tid & 63;
        const int w = tid >> 6;
        const int arow = w * 16 + (lane & 15);
        const int grow = rowBase + arow;
        const int growc = (grow < NN) ? grow : (NN - 1);
        const int koff8 = (lane >> 4) * 8;
        const int koff = (lane >> 4) * 16;

        f32x4 acc[9];
#pragma unroll
        for (int n = 0; n < 9; ++n) acc[n] = (f32x4){0.f, 0.f, 0.f, 0.f};

#pragma unroll
        for (int kk = 0; kk < 4; ++kk) {
            const float* xp = x + (size_t)growc * INF_ + kk * 32 + koff8;
            const float4 f0 = *(const float4*)xp;
            const float4 f1 = *(const float4*)(xp + 4);
            union { bf16x8 v; unsigned short u[8]; } au;
            au.u[0] = f2bf(f0.x); au.u[1] = f2bf(f0.y);
            au.u[2] = f2bf(f0.z); au.u[3] = f2bf(f0.w);
            au.u[4] = f2bf(f1.x); au.u[5] = f2bf(f1.y);
            au.u[6] = f2bf(f1.z); au.u[7] = f2bf(f1.w);
#pragma unroll
            for (int n = 0; n < 9; ++n) {
                const int brow = n * 16 + (lane & 15);
                const bf16x8 b = *(const bf16x8*)(sB + brow * LDA + kk * 64 + koff);
                acc[n] = __builtin_amdgcn_mfma_f32_16x16x32_bf16(au.v, b, acc[n], 0, 0, 0);
            }
        }

        const int rbase = rowBase + w * 16 + (lane >> 4) * 4;
#pragma unroll
        for (int n = 0; n < 8; ++n) {
            const int cc = n * 16 + (lane & 15);
#pragma unroll
            for (int r = 0; r < 4; ++r) {
                const int rw = rbase + r;
                if (rw < NN) hb[(size_t)rw * OC + cc] = __float2bfloat16(acc[n][r]);
            }
        }
        const int cp = lane & 15;
        if (cp < 8) {
            const int hd = cp & 3;
            float* dst = (cp < 4) ? al : ar;
#pragma unroll
            for (int r = 0; r < 4; ++r) {
                const int rw = rbase + r;
                if (rw < NN) dst[rw * NH + hd] = acc[8][r];
            }
        }
    } else {
        // ---- part1 path: coarse partition into bin-grouped packed words ----
        int* h     = (int*)smem;
        int* gbase = h + NBIN;
        int* lcur  = gbase + NBIN;
        const int pb = blockIdx.x / 5;    // 0..390
        const int t = tid;
        for (int i = t; i < NBIN; i += 256) { h[i] = 0; lcur[i] = 0; }
        __syncthreads();

        const int e0 = pb * EPB + t * EPT;
        int r[EPT], c[EPT];
        if (e0 + EPT <= NE) {
#pragma unroll
            for (int q = 0; q < EPT / 4; ++q) {
                const int4 rv = *(const int4*)&row[e0 + q * 4];
                const int4 cv = *(const int4*)&col[e0 + q * 4];
                r[q*4+0] = rv.x; r[q*4+1] = rv.y; r[q*4+2] = rv.z; r[q*4+3] = rv.w;
                c[q*4+0] = cv.x; c[q*4+1] = cv.y; c[q*4+2] = cv.z; c[q*4+3] = cv.w;
            }
        } else {
#pragma unroll
            for (int i = 0; i < EPT; ++i) {
                const int e = e0 + i;
                r[i] = (e < NE) ? row[e] : -1;
                c[i] = (e < NE) ? col[e] : 0;
            }
        }
#pragma unroll
        for (int i = 0; i < EPT; ++i)
            if (r[i] >= 0) atomicAdd(&h[r[i] >> BSH], 1);
        __syncthreads();
        for (int i = t; i < NBIN; i += 256)
            if (h[i]) gbase[i] = atomicAdd(&bincur[i], h[i]);
        __syncthreads();
#pragma unroll
        for (int i = 0; i < EPT; ++i) {
            if (r[i] < 0) continue;
            const int b = r[i] >> BSH;
            const int pos = atomicAdd(&lcur[b], 1);
            tmp[gbase[b] + pos] =
                ((unsigned)(r[i] & (BINW - 1)) << 17) | (unsigned)c[i];
        }
    }
}

// Fused fine-partition + aggregation: one 512-thread block per bin.
// Phase 1: bin's packed edges -> LDS, histogram its 128 nodes, 4-aligned
// start scan, scatter into LDS scols. Phase 2: 8 waves x 4 groups aggregate
// the 128 nodes straight from LDS.
__global__ __launch_bounds__(512) void k_p2agg(
    const unsigned* __restrict__ tmp, const int* __restrict__ bincur,
    const float* __restrict__ al, const float* __restrict__ ar,
    const __hip_bfloat16* __restrict__ hb, float* __restrict__ out) {
    __shared__ __align__(16) unsigned stage[CAPB];      // 10.2 KB
    __shared__ __align__(16) int scols[SCOLS_CAP];      // 12.0 KB
    __shared__ int h[BINW], st[BINW], cur[BINW], ts[BINW];
    const int b = blockIdx.x;
    const int t = threadIdx.x;                          // 0..511
    const int gs = b * CAPB;
    const int cnt = bincur[b] - gs;

    if (t < BINW) h[t] = 0;
    __syncthreads();
    for (int j = t; j < cnt; j += 512) {
        const unsigned p = tmp[gs + j];
        stage[j] = p;
        atomicAdd(&h[p >> 17], 1);
    }
    __syncthreads();
    // scan of 4-aligned sizes over 128 nodes (threads 0..127)
    if (t < BINW) ts[t] = (h[t] + 3) & ~3;
    __syncthreads();
    for (int o = 1; o < BINW; o <<= 1) {
        const int add = (t >= o && t < BINW) ? ts[t - o] : 0;
        __syncthreads();
        if (t < BINW) ts[t] += add;
        __syncthreads();
    }
    if (t < BINW) {
        const int s = ts[t] - ((h[t] + 3) & ~3);
        st[t] = s;
        cur[t] = s;
    }
    __syncthreads();
    for (int j = t; j < cnt; j += 512) {
        const unsigned p = stage[j];
        const int pos = atomicAdd(&cur[p >> 17], 1);
        scols[pos] = (int)(p & 0x1FFFFu);
    }
    __syncthreads();

    // Phase 2: aggregation. 8 waves x 4 groups = 32 nodes per round, 4 rounds.
    const int w = t >> 6;
    const int lane = t & 63;
    const int g = lane >> 4;
    const int sl = lane & 15;
    const int hsel = sl >> 2;
    const int je = sl >> 2;
    const int sh = sl & 3;
    const int sbase = lane & 48;
    const char* hrow = (const char*)hb + sl * 16;

    for (int rnd = 0; rnd < BINW / 32; ++rnd) {
        const int ln = rnd * 32 + w * 4 + g;
        const int node = b * BINW + ln;
        if (node >= NN) continue;
        const int start = st[ln];
        const int deg = h[ln];
        const float al_sh = al[node * NH + sh];

        f32x2 a0 = {0.f, 0.f}, a1 = {0.f, 0.f}, a2 = {0.f, 0.f}, a3 = {0.f, 0.f};
        float ssum = 0.f;

        int4 cA = *(const int4*)(scols + start);
        int4 cB = *(const int4*)(scols + start + 4);

        for (int kk = 0; kk < deg; kk += 8) {
            const int rem = deg - kk;
            const int4 cA2 = *(const int4*)(scols + start + kk + 8);
            const int4 cB2 = *(const int4*)(scols + start + kk + 12);

            float wvA = 0.f, wvB = 0.f;
            if (je < rem) {
                const int c = sel4(cA, je);
                wvA = __expf(lrelu(al_sh + ar[c * NH + sh]));
            }
            if (je + 4 < rem) {
                const int c = sel4(cB, je);
                wvB = __expf(lrelu(al_sh + ar[c * NH + sh]));
            }

            int c_[8] = {cA.x, cA.y, cA.z, cA.w, cB.x, cB.y, cB.z, cB.w};
#pragma unroll
            for (int j = 0; j < 8; ++j)
                if (j >= rem) c_[j] = 0;

#pragma unroll
            for (int j = 0; j < 8; ++j) {
                const float wj = __shfl(j < 4 ? wvA : wvB, sbase + (j & 3) * 4 + hsel);
                const uint4 v = *(const uint4*)(hrow + (size_t)c_[j] * 256);
                a0 += wj * (f32x2){__uint_as_float(v.x << 16), __uint_as_float(v.x & 0xffff0000u)};
                a1 += wj * (f32x2){__uint_as_float(v.y << 16), __uint_as_float(v.y & 0xffff0000u)};
                a2 += wj * (f32x2){__uint_as_float(v.z << 16), __uint_as_float(v.z & 0xffff0000u)};
                a3 += wj * (f32x2){__uint_as_float(v.w << 16), __uint_as_float(v.w & 0xffff0000u)};
                ssum += wj;
            }
            cA = cA2; cB = cB2;
        }

        const float inv = (ssum > 0.f) ? 1.0f / ssum : 0.f;
        float4 o0, o1;
        o0.x = a0.x * inv; o0.y = a0.y * inv; o0.z = a1.x * inv; o0.w = a1.y * inv;
        o1.x = a2.x * inv; o1.y = a2.y * inv; o1.z = a3.x * inv; o1.w = a3.y * inv;
        float* dst = out + (size_t)node * OC + sl * 8;
        *(float4*)dst = o0;
        *(float4*)(dst + 4) = o1;
    }
}

extern "C" void kernel_launch(void* const* d_in, const int* in_sizes, int n_in,
                              void* d_out, int out_size, void* d_ws, size_t ws_size,
                              hipStream_t stream) {
    const float* x    = (const float*)d_in[0];
    const int*   ei   = (const int*)d_in[1];    // [2, NE]
    const float* W    = (const float*)d_in[2];
    const float* a_l  = (const float*)d_in[3];
    const float* a_r  = (const float*)d_in[4];
    float* out = (float*)d_out;

    const int* row = ei;         // destination
    const int* col = ei + NE;    // source

    char* ws = (char*)d_ws;
    __hip_bfloat16* hb = (__hip_bfloat16*)ws;   ws += (size_t)NN * OC * 2;      // 25.6 MB
    __hip_bfloat16* Wt = (__hip_bfloat16*)ws;   ws += (size_t)144 * 128 * 2;    // 36 KB
    float*    al      = (float*)ws;             ws += (size_t)NN * NH * 4;
    float*    ar      = (float*)ws;             ws += (size_t)NN * NH * 4;
    unsigned* tmp     = (unsigned*)ws;          ws += (size_t)NBIN * CAPB * 4;  // 8.0 MB
    int*      bincur  = (int*)ws;               ws += (size_t)NBIN * 4;

    k_pre<<<72, 256, 0, stream>>>(W, a_l, a_r, Wt, bincur);
    k_gp1<<<1955, 256, 0, stream>>>(x, Wt, hb, al, ar, row, col, bincur, tmp);
    k_p2agg<<<NBIN, 512, 0, stream>>>(tmp, bincur, al, ar, hb, out);
}